// Round 17
// baseline (1206.391 us; speedup 1.0000x reference)
//
#include <hip/hip_runtime.h>
#include <hip/hip_bf16.h>

// ---------------------------------------------------------------------------
// RWKV7 attention block — Round 17.
// Minv folded into chunk tensors in cprep: AM = Minv@At (stored over At in
// KK16), LM = Minv@strict_lower(At@Kt^T) (hi/lo, old Minv region). recchunk
// collapses to 2 compute phases / 3 barriers per chunk (was 4 phases / 4).
// 9 kernel launches.  B=8, T=2048, H=1024, NH=16. ws ~247.4 MB.
// ---------------------------------------------------------------------------

#define DEVI __device__ __forceinline__

constexpr int TSEQ = 2048;
constexpr int HID  = 1024;
constexpr int BTOT = 16384;   // B*T
constexpr int CCH  = 32;      // chunk length
constexpr int NCH  = TSEQ / CCH;
constexpr int L4N  = 352;     // combined lora hidden width
constexpr float W_SCALE = -0.6065306597126334f;
constexpr float GN_EPS  = 6.4e-4f;   // 64 * 1e-5

using s16x8  = __attribute__((ext_vector_type(8))) short;
using f32x4v = __attribute__((ext_vector_type(4))) float;

DEVI float4 ld4(const float* p) { return *reinterpret_cast<const float4*>(p); }
DEVI void   st4(float* p, float4 v) { *reinterpret_cast<float4*>(p) = v; }
DEVI float  sigf(float x) { return 1.0f / (1.0f + __expf(-x)); }
DEVI unsigned short bfr(float f) {
    unsigned int u = __float_as_uint(f);
    return (unsigned short)((u + 0x7fffu + ((u >> 16) & 1u)) >> 16);
}
DEVI float bff(unsigned short s) { return __uint_as_float(((unsigned int)s) << 16); }
DEVI unsigned int pk2(float lo, float hi) {
    return ((unsigned int)bfr(hi) << 16) | (unsigned int)bfr(lo);
}
DEVI void up8(uint4 u, float* f) {
    f[0]=bff((unsigned short)(u.x & 0xffffu)); f[1]=bff((unsigned short)(u.x >> 16));
    f[2]=bff((unsigned short)(u.y & 0xffffu)); f[3]=bff((unsigned short)(u.y >> 16));
    f[4]=bff((unsigned short)(u.z & 0xffffu)); f[5]=bff((unsigned short)(u.z >> 16));
    f[6]=bff((unsigned short)(u.w & 0xffffu)); f[7]=bff((unsigned short)(u.w >> 16));
}
DEVI f32x4v MF(s16x8 a, s16x8 b, f32x4v c) {
    return __builtin_amdgcn_mfma_f32_16x16x32_bf16(a, b, c, 0, 0, 0);
}
DEVI void gl16(const void* g, void* l) {
    __builtin_amdgcn_global_load_lds(
        (const __attribute__((address_space(1))) unsigned int*)g,
        (__attribute__((address_space(3))) unsigned int*)l, 16, 0, 0);
}
DEVI void gl4(const void* g, void* l) {
    __builtin_amdgcn_global_load_lds(
        (const __attribute__((address_space(1))) unsigned int*)g,
        (__attribute__((address_space(3))) unsigned int*)l, 4, 0, 0);
}

// ---------------------------------------------------------------------------
// cast_all: 12 f32->bf16 segments, prefix-offset table (R16-fixed).
// ---------------------------------------------------------------------------
struct CastArgs {
    const float* src[12];
    unsigned short* dst[12];
    int start4[13];
};
__global__ __launch_bounds__(256) void cast_all_kernel(CastArgs a) {
    int i4 = blockIdx.x * 256 + threadIdx.x;
    if (i4 >= a.start4[12]) return;
    int seg = 0;
#pragma unroll
    for (int s = 1; s < 12; s++) seg += (i4 >= a.start4[s]) ? 1 : 0;
    int off = (i4 - a.start4[seg]) * 4;
    float4 v = ld4(a.src[seg] + off);
    ushort4 o; o.x = bfr(v.x); o.y = bfr(v.y); o.z = bfr(v.z); o.w = bfr(v.w);
    *reinterpret_cast<ushort4*>(a.dst[seg] + off) = o;
}

// ---------------------------------------------------------------------------
// proj3 (unchanged): fused r/k/v projections.
// ---------------------------------------------------------------------------
__global__ __launch_bounds__(256) void proj3_kernel(
        const float* __restrict__ x,
        const float* __restrict__ cr, const float* __restrict__ ck,
        const float* __restrict__ cv,
        const unsigned short* __restrict__ Wr, const unsigned short* __restrict__ Wk,
        const unsigned short* __restrict__ Wv,
        unsigned short* __restrict__ Ro, unsigned short* __restrict__ Ko,
        unsigned short* __restrict__ Vo) {
    __shared__ __align__(16) unsigned short As[3][64 * 32];
    __shared__ __align__(16) unsigned short Bs[3][128 * 32];
    const int tid = threadIdx.x;
    const int w = tid >> 6, l = tid & 63;
    const int bm = blockIdx.x * 64, bn = blockIdx.y * 128;
    const int wm = w >> 1, wn = w & 1;
    const int lr = l & 15, lq = l >> 4, lk = lq * 8;

    f32x4v acc[3][2][4];
#pragma unroll
    for (int p = 0; p < 3; p++)
#pragma unroll
        for (int i = 0; i < 2; i++)
#pragma unroll
            for (int j = 0; j < 4; j++)
#pragma unroll
                for (int q = 0; q < 4; q++) acc[p][i][j][q] = 0.f;

    const float* cvs[3] = {cr, ck, cv};
    const unsigned short* Ws[3] = {Wr, Wk, Wv};

    for (int k0 = 0; k0 < HID; k0 += 32) {
        {
            const int row = tid >> 2, kp = (tid & 3) * 8;
            const int gr = bm + row;
            const float* xp = x + (size_t)gr * HID + k0 + kp;
            float4 x0 = ld4(xp), x1 = ld4(xp + 4);
            float4 p0 = make_float4(0.f, 0.f, 0.f, 0.f), p1 = p0;
            if ((gr & (TSEQ - 1)) != 0) { p0 = ld4(xp - HID); p1 = ld4(xp - HID + 4); }
            float xb[8] = {x0.x, x0.y, x0.z, x0.w, x1.x, x1.y, x1.z, x1.w};
            float dx[8] = {p0.x - x0.x, p0.y - x0.y, p0.z - x0.z, p0.w - x0.w,
                           p1.x - x1.x, p1.y - x1.y, p1.z - x1.z, p1.w - x1.w};
#pragma unroll
            for (int p = 0; p < 3; p++) {
                float4 c0 = ld4(cvs[p] + k0 + kp), c1 = ld4(cvs[p] + k0 + kp + 4);
                float cc[8] = {c0.x, c0.y, c0.z, c0.w, c1.x, c1.y, c1.z, c1.w};
                uint4 u;
                u.x = pk2(fmaf(dx[0], cc[0], xb[0]), fmaf(dx[1], cc[1], xb[1]));
                u.y = pk2(fmaf(dx[2], cc[2], xb[2]), fmaf(dx[3], cc[3], xb[3]));
                u.z = pk2(fmaf(dx[4], cc[4], xb[4]), fmaf(dx[5], cc[5], xb[5]));
                u.w = pk2(fmaf(dx[6], cc[6], xb[6]), fmaf(dx[7], cc[7], xb[7]));
                *reinterpret_cast<uint4*>(&As[p][row * 32 + kp]) = u;
            }
        }
#pragma unroll
        for (int p = 0; p < 3; p++)
#pragma unroll
            for (int c = 0; c < 2; c++) {
                int idx = c * 256 + tid;
                int rw = idx >> 2, kp2 = (idx & 3) * 8;
                gl16(Ws[p] + (size_t)(bn + rw) * HID + k0 + kp2,
                     &Bs[p][c * 2048 + w * 512]);
            }
        __syncthreads();
#pragma unroll
        for (int p = 0; p < 3; p++) {
            s16x8 af[2], bf4[4];
#pragma unroll
            for (int i = 0; i < 2; i++)
                af[i] = *reinterpret_cast<const s16x8*>(
                    &As[p][(wm * 32 + i * 16 + lr) * 32 + lk]);
#pragma unroll
            for (int j = 0; j < 4; j++)
                bf4[j] = *reinterpret_cast<const s16x8*>(
                    &Bs[p][(wn * 64 + j * 16 + lr) * 32 + lk]);
#pragma unroll
            for (int i = 0; i < 2; i++)
#pragma unroll
                for (int j = 0; j < 4; j++)
                    acc[p][i][j] = MF(af[i], bf4[j], acc[p][i][j]);
        }
        __syncthreads();
    }

    unsigned short* dsts[3] = {Ro, Ko, Vo};
#pragma unroll
    for (int p = 0; p < 3; p++)
#pragma unroll
        for (int i = 0; i < 2; i++)
#pragma unroll
            for (int j = 0; j < 4; j++)
#pragma unroll
                for (int q = 0; q < 4; q++) {
                    const int grow = bm + wm * 32 + i * 16 + lq * 4 + q;
                    const int gcol = bn + wn * 64 + j * 16 + lr;
                    dsts[p][(size_t)grow * HID + gcol] = bfr(acc[p][i][j][q]);
                }
}

// ---------------------------------------------------------------------------
// lora4 (unchanged): fused v/w/a/g lora stage-1 -> H1[BTOT][352].
// ---------------------------------------------------------------------------
__global__ __launch_bounds__(256) void lora4_kernel(
        const float* __restrict__ x,
        const float* __restrict__ cv_, const float* __restrict__ cw_,
        const float* __restrict__ ca_, const float* __restrict__ cg_,
        const unsigned short* __restrict__ LW, unsigned short* __restrict__ H1) {
    __shared__ __align__(16) unsigned short As[4][64 * 32];
    __shared__ __align__(16) unsigned short Bs[L4N * 32];
    const int tid = threadIdx.x;
    const int w = tid >> 6, l = tid & 63;
    const int lr = l & 15, lq = l >> 4, lk = lq * 8;
    const int bm = blockIdx.x * 64;
    const float* cvs[4] = {cv_, cw_, ca_, cg_};

    f32x4v acc[22];
#pragma unroll
    for (int j = 0; j < 22; j++)
#pragma unroll
        for (int q = 0; q < 4; q++) acc[j][q] = 0.f;

    for (int k0 = 0; k0 < HID; k0 += 32) {
        {
            const int row = tid >> 2, kp = (tid & 3) * 8;
            const int gr = bm + row;
            const float* xp = x + (size_t)gr * HID + k0 + kp;
            float4 x0 = ld4(xp), x1 = ld4(xp + 4);
            float4 p0 = make_float4(0.f, 0.f, 0.f, 0.f), p1 = p0;
            if ((gr & (TSEQ - 1)) != 0) { p0 = ld4(xp - HID); p1 = ld4(xp - HID + 4); }
            float xb[8] = {x0.x, x0.y, x0.z, x0.w, x1.x, x1.y, x1.z, x1.w};
            float dx[8] = {p0.x - x0.x, p0.y - x0.y, p0.z - x0.z, p0.w - x0.w,
                           p1.x - x1.x, p1.y - x1.y, p1.z - x1.z, p1.w - x1.w};
#pragma unroll
            for (int p = 0; p < 4; p++) {
                float4 c0 = ld4(cvs[p] + k0 + kp), c1 = ld4(cvs[p] + k0 + kp + 4);
                float cc[8] = {c0.x, c0.y, c0.z, c0.w, c1.x, c1.y, c1.z, c1.w};
                uint4 u;
                u.x = pk2(fmaf(dx[0], cc[0], xb[0]), fmaf(dx[1], cc[1], xb[1]));
                u.y = pk2(fmaf(dx[2], cc[2], xb[2]), fmaf(dx[3], cc[3], xb[3]));
                u.z = pk2(fmaf(dx[4], cc[4], xb[4]), fmaf(dx[5], cc[5], xb[5]));
                u.w = pk2(fmaf(dx[6], cc[6], xb[6]), fmaf(dx[7], cc[7], xb[7]));
                *reinterpret_cast<uint4*>(&As[p][row * 32 + kp]) = u;
            }
        }
#pragma unroll
        for (int c = 0; c < 6; c++) {
            int idx = c * 256 + tid;
            if (idx < L4N * 4) {
                gl16(LW + (size_t)(idx >> 2) * HID + (idx & 3) * 8 + k0,
                     (char*)&Bs[0] + (c * 256 + w * 64) * 16);
            }
        }
        __syncthreads();
        s16x8 af[4];
#pragma unroll
        for (int p = 0; p < 4; p++)
            af[p] = *reinterpret_cast<const s16x8*>(&As[p][(w * 16 + lr) * 32 + lk]);
#pragma unroll
        for (int j = 0; j < 22; j++) {
            const int grp = (j < 4) ? 0 : (j < 8) ? 1 : (j < 12) ? 2 : 3;
            s16x8 bf = *reinterpret_cast<const s16x8*>(&Bs[(j * 16 + lr) * 32 + lk]);
            acc[j] = MF(af[grp], bf, acc[j]);
        }
        __syncthreads();
    }

#pragma unroll
    for (int j = 0; j < 22; j++)
#pragma unroll
        for (int q = 0; q < 4; q++) {
            const int grow = bm + w * 16 + lq * 4 + q;
            const int gcol = j * 16 + lr;
            float d = acc[j][q];
            if (j >= 4 && j < 8) d = tanhf(d);
            else if (j >= 12) d = sigf(d);
            H1[(size_t)grow * L4N + gcol] = bfr(d);
        }
}

// ---------------------------------------------------------------------------
// stage2 (unchanged): v/w/a lora stage-2 in one launch (blockIdx.z).
// ---------------------------------------------------------------------------
__global__ __launch_bounds__(256) void stage2_kernel(
        const unsigned short* __restrict__ H1,
        const unsigned short* __restrict__ vB16, const unsigned short* __restrict__ wB16,
        const unsigned short* __restrict__ aB16,
        const float* __restrict__ vb, const float* __restrict__ wb,
        const float* __restrict__ ab,
        unsigned short* __restrict__ Vout, unsigned short* __restrict__ Wout,
        unsigned short* __restrict__ Aout,
        const unsigned short* __restrict__ aux1, const float* __restrict__ aux2) {
    const int z = blockIdx.z;
    const unsigned short* Bw = (z == 0) ? vB16 : (z == 1) ? wB16 : aB16;
    const float* bias = (z == 0) ? vb : (z == 1) ? wb : ab;
    unsigned short* Cout = (z == 0) ? Vout : (z == 1) ? Wout : Aout;
    const int aoff = z * 64;
    __shared__ __align__(16) unsigned short As[128 * 32];
    __shared__ __align__(16) unsigned short Bs[128 * 32];
    const int tid = threadIdx.x;
    const int w = tid >> 6, l = tid & 63;
    const int bm = blockIdx.x * 128, bn = blockIdx.y * 128;
    const int wm = w >> 1, wn = w & 1;
    const int lr = l & 15, lk = (l >> 4) * 8;

    f32x4v acc[4][4];
#pragma unroll
    for (int i = 0; i < 4; i++)
#pragma unroll
        for (int j = 0; j < 4; j++)
#pragma unroll
            for (int q = 0; q < 4; q++) acc[i][j][q] = 0.f;

    for (int k0 = 0; k0 < 64; k0 += 32) {
#pragma unroll
        for (int c = 0; c < 2; c++) {
            int idx = c * 256 + tid;
            int row = idx >> 2, kp = (idx & 3) * 8;
            gl16(H1 + (size_t)(bm + row) * L4N + aoff + k0 + kp,
                 &As[c * 2048 + w * 512]);
        }
#pragma unroll
        for (int c = 0; c < 2; c++) {
            int idx = c * 256 + tid;
            int row = idx >> 2, kp = (idx & 3) * 8;
            gl16(Bw + (size_t)(bn + row) * 64 + k0 + kp, &Bs[c * 2048 + w * 512]);
        }
        __syncthreads();
        s16x8 afx[4], bfx[4];
#pragma unroll
        for (int i = 0; i < 4; i++)
            afx[i] = *reinterpret_cast<const s16x8*>(&As[(wm * 64 + i * 16 + lr) * 32 + lk]);
#pragma unroll
        for (int j = 0; j < 4; j++)
            bfx[j] = *reinterpret_cast<const s16x8*>(&Bs[(wn * 64 + j * 16 + lr) * 32 + lk]);
#pragma unroll
        for (int i = 0; i < 4; i++)
#pragma unroll
            for (int j = 0; j < 4; j++)
                acc[i][j] = MF(afx[i], bfx[j], acc[i][j]);
        __syncthreads();
    }

#pragma unroll
    for (int i = 0; i < 4; i++) {
        const int grow0 = bm + wm * 64 + i * 16 + (l >> 4) * 4;
#pragma unroll
        for (int j = 0; j < 4; j++) {
            const int gcol = bn + wn * 64 + j * 16 + lr;
            const float bsv = bias[gcol];
#pragma unroll
            for (int q = 0; q < 4; q++) {
                const int grow = grow0 + q;
                float d = acc[i][j][q];
                if (z == 0) {
                    float v0 = bff(aux1[(size_t)grow * HID + gcol]);
                    d = fmaf(aux2[(size_t)grow * HID + gcol] - v0, sigf(d + bsv), v0);
                } else if (z == 1) {
                    d = W_SCALE * sigf(d + bsv);
                } else {
                    d = sigf(d + bsv);
                }
                Cout[(size_t)grow * HID + gcol] = bfr(d);
            }
        }
    }
}

// ---------------------------------------------------------------------------
// mgemm (unchanged; the g stage-2).
// ---------------------------------------------------------------------------
template<int BM, int BN, int MODE, bool OUTBF>
__global__ __launch_bounds__(256) void mgemm(
        const unsigned short* __restrict__ Ab, const unsigned short* __restrict__ Bw,
        void* Cout, int N, int K, int lda,
        const float* __restrict__ bias,
        const unsigned short* aux1, const float* __restrict__ aux2) {
    constexpr int BK = 32;
    constexpr int WM_ = (BN == 128) ? 2 : 4;
    constexpr int WN_ = (BN == 128) ? 2 : 1;
    constexpr int WTM = BM / WM_, WTN = BN / WN_;
    constexpr int MF_ = WTM / 16, NF = WTN / 16;
    constexpr int ACALLS = (BM * BK) / 2048;
    constexpr int BCALLS = (BN * BK) / 2048;
    __shared__ __align__(16) unsigned short As[BM * BK];
    __shared__ __align__(16) unsigned short Bs[BN * BK];
    const int tid = threadIdx.x;
    const int w = tid >> 6, l = tid & 63;
    const int bm = blockIdx.x * BM, bn = blockIdx.y * BN;
    const int wm = w / WN_, wn = w % WN_;
    const int lr = l & 15, lk = (l >> 4) * 8;

    f32x4v acc[MF_][NF];
#pragma unroll
    for (int i = 0; i < MF_; i++)
#pragma unroll
        for (int j = 0; j < NF; j++)
#pragma unroll
            for (int q = 0; q < 4; q++) acc[i][j][q] = 0.f;

    for (int k0 = 0; k0 < K; k0 += BK) {
#pragma unroll
        for (int c = 0; c < ACALLS; c++) {
            int idx = c * 256 + tid;
            int row = idx >> 2, kp = (idx & 3) * 8;
            gl16(Ab + (size_t)(bm + row) * lda + k0 + kp, &As[c * 2048 + w * 512]);
        }
#pragma unroll
        for (int c = 0; c < BCALLS; c++) {
            int idx = c * 256 + tid;
            int row = idx >> 2, kp = (idx & 3) * 8;
            int gc = bn + row; if (gc > N - 1) gc = N - 1;
            gl16(Bw + (size_t)gc * K + k0 + kp, &Bs[c * 2048 + w * 512]);
        }
        __syncthreads();
        s16x8 afx[MF_], bfx[NF];
#pragma unroll
        for (int i = 0; i < MF_; i++)
            afx[i] = *reinterpret_cast<const s16x8*>(&As[(wm * WTM + i * 16 + lr) * BK + lk]);
#pragma unroll
        for (int j = 0; j < NF; j++)
            bfx[j] = *reinterpret_cast<const s16x8*>(&Bs[(wn * WTN + j * 16 + lr) * BK + lk]);
#pragma unroll
        for (int i = 0; i < MF_; i++)
#pragma unroll
            for (int j = 0; j < NF; j++)
                acc[i][j] = __builtin_amdgcn_mfma_f32_16x16x32_bf16(
                    afx[i], bfx[j], acc[i][j], 0, 0, 0);
        __syncthreads();
    }

#pragma unroll
    for (int i = 0; i < MF_; i++) {
        const int grow0 = bm + wm * WTM + i * 16 + (l >> 4) * 4;
#pragma unroll
        for (int j = 0; j < NF; j++) {
            const int gcol = bn + wn * WTN + j * 16 + lr;
            if (gcol >= N) continue;
#pragma unroll
            for (int q = 0; q < 4; q++) {
                const int grow = grow0 + q;
                float d = acc[i][j][q];
                if (OUTBF) ((unsigned short*)Cout)[(size_t)grow * N + gcol] = bfr(d);
                else       ((float*)Cout)[(size_t)grow * N + gcol] = d;
            }
        }
    }
}

// ---------------------------------------------------------------------------
// cprep v2: prep + chunkprep + Minv + FOLDED tensors.
//   row loop: kk,b,kn,Rt scaling, s3, Ed (At NOT written to global).
//   Mab = strict_lower(At@Bt^T), Mak = strict_lower(At@Kt^T) via MFMA.
//   fsub -> Minv (f32, LDS).  LM = Minv@Mak -> hi/lo global (old Minv region).
//   AM = Minv@At -> bf16 into KK16 rows (replaces At).
// ---------------------------------------------------------------------------
__global__ __launch_bounds__(64) void cprep_kernel(
        unsigned short* __restrict__ K16, unsigned short* __restrict__ A16,
        unsigned short* __restrict__ R16, unsigned short* __restrict__ KK16,
        const unsigned short* __restrict__ W16,
        const float* __restrict__ kkc, const float* __restrict__ kac,
        const float* __restrict__ rkw,
        float* __restrict__ SB, float* __restrict__ Ed,
        unsigned short* __restrict__ MvH, unsigned short* __restrict__ MvL) {
    __shared__ __align__(16) unsigned short sA[32][64], sB[32][64], sK[32][64];
    __shared__ __align__(16) float Mab[32][36], Mak[32][36], Mnv[32][36];
    const int bid = blockIdx.x;
    const int bh = bid >> 6, ch = bid & 63;
    const int bb = bh >> 4, hh = bh & 15;
    const int l = threadIdx.x;
    const int chn = hh * 64 + l;
    const float kkcv = kkc[chn], kacv = kac[chn], rkv = rkw[chn];
    const size_t off0 = ((size_t)(bb * TSEQ) + ch * CCH) * HID + chn;
    size_t off = off0;
    float cw = 0.f, er = 1.f;
    for (int i = 0; i < CCH; i++, off += HID) {
        const float k = bff(K16[off]);
        const float a = bff(A16[off]);
        const float r = bff(R16[off]);
        const float wv = bff(W16[off]);
        const float kr = k * kkcv;
        float ss = kr * kr;
        ss += __shfl_xor(ss, 1);  ss += __shfl_xor(ss, 2);
        ss += __shfl_xor(ss, 4);  ss += __shfl_xor(ss, 8);
        ss += __shfl_xor(ss, 16); ss += __shfl_xor(ss, 32);
        const float inv = 1.0f / fmaxf(sqrtf(ss), 1e-12f);
        const float kk = kr * inv;
        const float b  = kk * a;
        const float kn = k * fmaf(a - 1.0f, kacv, 1.0f);
        float s3 = r * kn * rkv;
        s3 += __shfl_xor(s3, 1);  s3 += __shfl_xor(s3, 2);
        s3 += __shfl_xor(s3, 4);  s3 += __shfl_xor(s3, 8);
        s3 += __shfl_xor(s3, 16); s3 += __shfl_xor(s3, 32);
        if (l == 0) SB[(size_t)bh * TSEQ + ch * CCH + i] = s3;
        const float cwp = cw; cw += wv;
        const float ea = __expf(cwp), ei = __expf(-cw);
        er = __expf(cw);
        const unsigned short At = bfr(-kk * ea);
        const unsigned short Bt = bfr(b * ei);
        const unsigned short Kt = bfr(kn * ei);
        A16[off] = Bt;
        K16[off] = Kt;
        R16[off] = bfr(r * er);
        sA[i][l] = At; sB[i][l] = Bt; sK[i][l] = Kt;
    }
    Ed[((size_t)bh * NCH + ch) * 64 + l] = er;
    __syncthreads();
    const int lr = l & 15, lq = l >> 4;
    f32x4v z4; z4[0] = z4[1] = z4[2] = z4[3] = 0.f;
#pragma unroll
    for (int mi = 0; mi < 2; mi++)
#pragma unroll
        for (int ni = 0; ni < 2; ni++) {
            s16x8 a0 = *reinterpret_cast<const s16x8*>(&sA[mi * 16 + lr][lq * 8]);
            s16x8 a1 = *reinterpret_cast<const s16x8*>(&sA[mi * 16 + lr][32 + lq * 8]);
            s16x8 b0 = *reinterpret_cast<const s16x8*>(&sB[ni * 16 + lr][lq * 8]);
            s16x8 b1 = *reinterpret_cast<const s16x8*>(&sB[ni * 16 + lr][32 + lq * 8]);
            s16x8 k0 = *reinterpret_cast<const s16x8*>(&sK[ni * 16 + lr][lq * 8]);
            s16x8 k1 = *reinterpret_cast<const s16x8*>(&sK[ni * 16 + lr][32 + lq * 8]);
            f32x4v m  = MF(a1, b1, MF(a0, b0, z4));
            f32x4v mk = MF(a1, k1, MF(a0, k0, z4));
#pragma unroll
            for (int q = 0; q < 4; q++) {
                int r = mi * 16 + lq * 4 + q, cc2 = ni * 16 + lr;
                Mab[r][cc2] = (cc2 < r) ? m[q] : 0.f;
                Mak[r][cc2] = (cc2 < r) ? mk[q] : 0.f;
            }
        }
    __syncthreads();
    // forward substitution -> Minv columns (lane j), write to Mnv LDS
    const int j = l & 31;
    float m[32];
#pragma unroll
    for (int i = 0; i < 32; i++) m[i] = (i == j) ? 1.f : 0.f;
#pragma unroll
    for (int i = 1; i < 32; i++) {
        float p0 = 0.f, p1 = 0.f, p2 = 0.f, p3 = 0.f;
#pragma unroll
        for (int k4_ = 0; k4_ < 32; k4_ += 4) {
            if (k4_ >= i) break;
            float4 L4 = *reinterpret_cast<const float4*>(&Mab[i][k4_]);
            p0 = fmaf(L4.x, m[k4_ + 0], p0);
            if (k4_ + 1 < i) p1 = fmaf(L4.y, m[k4_ + 1], p1);
            if (k4_ + 2 < i) p2 = fmaf(L4.z, m[k4_ + 2], p2);
            if (k4_ + 3 < i) p3 = fmaf(L4.w, m[k4_ + 3], p3);
        }
        m[i] += (p0 + p1) + (p2 + p3);
    }
    if (l < 32) {
#pragma unroll
        for (int i = 0; i < 32; i++) Mnv[i][j] = m[i];
    }
    __syncthreads();
    // LM = Mnv @ Mak -> hi/lo global (each lane: 16 rows x fixed col t')
    {
        unsigned short* dH = MvH + (size_t)(bh * NCH + ch) * 1024;
        unsigned short* dL = MvL + (size_t)(bh * NCH + ch) * 1024;
        const int tp = l & 31;
        const int th = (l >> 5) * 16;
        for (int t = 0; t < 16; t++) {
            float s = 0.f;
#pragma unroll 8
            for (int jj = 0; jj < 32; jj++) s = fmaf(Mnv[th + t][jj], Mak[jj][tp], s);
            unsigned short h = bfr(s);
            dH[(th + t) * 32 + tp] = h;
            dL[(th + t) * 32 + tp] = bfr(s - bff(h));
        }
    }
    // AM = Mnv @ At -> bf16 into KK16 (lane owns column l)
    {
        size_t offr = off0;
        for (int t = 0; t < 32; t++, offr += HID) {
            float s = 0.f;
#pragma unroll 8
            for (int jj = 0; jj < 32; jj++) s = fmaf(Mnv[t][jj], bff(sA[jj][l]), s);
            KK16[offr] = bfr(s);
        }
    }
}

// ---------------------------------------------------------------------------
// Chunked recurrence v2: 2 compute phases / 3 barriers per chunk.
//   ph1: ni==0 waves: Mrk/Mrb (both halves) + oac0 = Rt@S;
//        ni==1 waves: SAT = S@AM^T + V^T@LM^T (hi/lo write).
//   ph2: ni==0: O = oac0 + lowincl(Mrk)@V + lowincl(Mrb)@SA -> bf16 store;
//        all: state += SAT@BtT + VT@KtT, Ed scale, hi/lo writeback.
// ---------------------------------------------------------------------------
__global__ __launch_bounds__(256) void recchunk_kernel(
        const unsigned short* __restrict__ AMG, const unsigned short* __restrict__ BtG,
        const unsigned short* __restrict__ KtG, const unsigned short* __restrict__ RtG,
        const unsigned short* __restrict__ V16, const float* __restrict__ Ed,
        const unsigned short* __restrict__ LMH, const unsigned short* __restrict__ LML,
        unsigned short* __restrict__ Ob16) {
    __shared__ __align__(16) unsigned short stT[2][4][CCH][64];   // AM,Bt,Kt,Rt
    __shared__ __align__(16) unsigned short stMh[2][32][32], stMl[2][32][32];  // LM
    __shared__ __align__(16) unsigned short stV[2][CCH][16];
    __shared__ __align__(16) float stEd[2][64];
    __shared__ __align__(16) unsigned short Shi[16][74], Slo[16][74];
    __shared__ __align__(16) unsigned short BtT[64][42], KtT[64][42];
    __shared__ __align__(16) unsigned short VT[16][42];
    __shared__ __align__(16) unsigned short MrkH[32][42], MrkL[32][42];
    __shared__ __align__(16) unsigned short MrbH[32][42], MrbL[32][42];
    __shared__ __align__(16) unsigned short SATh[16][42], SATl[16][42];

    const int bid = blockIdx.x;
    const int vq = bid >> 7, bh = bid & 127;
    const int tid = threadIdx.x;
    const int w = tid >> 6, l = tid & 63;
    const int lr = l & 15, lq = l >> 4;
    const int bb = bh >> 4, hh = bh & 15;
    const size_t rowoff = ((size_t)bb * TSEQ) * HID + hh * 64;
    const int mi = w >> 1, ni = w & 1;

    const int r8 = l >> 3, ck = l & 7;
    const int swz8 = (ck ^ r8) * 8;

    auto STAGE = [&](int buf, int cn) {
        if (cn >= NCH) return;
        const size_t cb = rowoff + (size_t)(cn * CCH) * HID;
        const unsigned short* srcs[4] = {AMG, BtG, KtG, RtG};
        const unsigned short* T = srcs[w];
#pragma unroll
        for (int c = 0; c < 4; c++)
            gl16(T + cb + (size_t)(c * 8 + r8) * HID + swz8, &stT[buf][w][c * 8][0]);
        if (w == 0) {
            gl16(V16 + cb + (size_t)(l >> 1) * HID + vq * 16 + (l & 1) * 8,
                 &stV[buf][0][0]);
            gl4(Ed + ((size_t)bh * NCH + cn) * 64 + l, &stEd[buf][0]);
        } else if (w == 1) {
#pragma unroll
            for (int c = 0; c < 2; c++)
                gl16(LMH + (size_t)(bh * NCH + cn) * 1024 + c * 512 + l * 8,
                     (char*)&stMh[buf][0][0] + c * 1024);
        } else if (w == 2) {
#pragma unroll
            for (int c = 0; c < 2; c++)
                gl16(LML + (size_t)(bh * NCH + cn) * 1024 + c * 512 + l * 8,
                     (char*)&stMl[buf][0][0] + c * 1024);
        }
    };

    for (int idx = tid; idx < 16 * 74; idx += 256) {
        ((unsigned short*)Shi)[idx] = 0;
        ((unsigned short*)Slo)[idx] = 0;
    }
    STAGE(0, 0);
    asm volatile("s_waitcnt vmcnt(0)" ::: "memory");
    __syncthreads();

    auto fragT = [&](int bf, int tn, int rbase, int kb) -> s16x8 {
        int row = rbase + lr;
        int chv = ((kb >> 3) + lq) ^ (row & 7);
        return *reinterpret_cast<const s16x8*>(
            (const char*)&stT[bf][tn][0][0] + row * 128 + chv * 16);
    };
    auto fragS = [&](const unsigned short (*Sx)[74], int kb) -> s16x8 {
        return *reinterpret_cast<const s16x8*>(&Sx[lr][kb + lq * 8]);
    };
    auto frag42 = [&](const unsigned short (*T)[42], int rbase) -> s16x8 {
        return *reinterpret_cast<const s16x8*>(&T[rbase + lr][lq * 8]);
    };

    f32x4v Sacc;
#pragma unroll
    for (int q = 0; q < 4; q++) Sacc[q] = 0.f;
    f32x4v z4; z4[0] = z4[1] = z4[2] = z4[3] = 0.f;

    int buf = 0;
    for (int c = 0; c < NCH; c++) {
        STAGE(buf ^ 1, c + 1);
        // ---- transposes (all threads) ----
        {
            const int tt = tid & 31, g8 = tid >> 5;
            const int ch = g8 ^ (tt & 7);
            uint4 bu = *reinterpret_cast<const uint4*>(&stT[buf][1][tt][ch * 8]);
            uint4 ku = *reinterpret_cast<const uint4*>(&stT[buf][2][tt][ch * 8]);
            unsigned int bw[4] = {bu.x, bu.y, bu.z, bu.w};
            unsigned int kw[4] = {ku.x, ku.y, ku.z, ku.w};
#pragma unroll
            for (int e = 0; e < 4; e++) {
                BtT[g8 * 8 + 2 * e][tt]     = (unsigned short)(bw[e] & 0xffffu);
                BtT[g8 * 8 + 2 * e + 1][tt] = (unsigned short)(bw[e] >> 16);
                KtT[g8 * 8 + 2 * e][tt]     = (unsigned short)(kw[e] & 0xffffu);
                KtT[g8 * 8 + 2 * e + 1][tt] = (unsigned short)(kw[e] >> 16);
            }
            if (g8 < 4) {
                ushort4 vu = *reinterpret_cast<const ushort4*>(&stV[buf][tt][g8 * 4]);
                VT[g8 * 4 + 0][tt] = vu.x; VT[g8 * 4 + 1][tt] = vu.y;
                VT[g8 * 4 + 2][tt] = vu.z; VT[g8 * 4 + 3][tt] = vu.w;
            }
        }
        __syncthreads();
        // ---- ph1 ----
        f32x4v oac = z4;
        if (ni == 0) {
            s16x8 rt0 = fragT(buf, 3, mi * 16, 0), rt1 = fragT(buf, 3, mi * 16, 32);
            s16x8 sh0 = fragS(Shi, 0), sh1 = fragS(Shi, 32);
            s16x8 sl0 = fragS(Slo, 0), sl1 = fragS(Slo, 32);
            oac = MF(rt1, sl1, MF(rt0, sl0, MF(rt1, sh1, MF(rt0, sh0, z4))));
#pragma unroll
            for (int n = 0; n < 2; n++) {
                s16x8 kt0 = fragT(buf, 2, n * 16, 0), kt1 = fragT(buf, 2, n * 16, 32);
                s16x8 bt0 = fragT(buf, 1, n * 16, 0), bt1 = fragT(buf, 1, n * 16, 32);
                f32x4v mrk = MF(rt1, kt1, MF(rt0, kt0, z4));
                f32x4v mrb = MF(rt1, bt1, MF(rt0, bt0, z4));
#pragma unroll
                for (int q = 0; q < 4; q++) {
                    const int r = mi * 16 + lq * 4 + q, cc = n * 16 + lr;
                    float vv = (cc <= r) ? mrk[q] : 0.f;
                    unsigned short h = bfr(vv);
                    MrkH[r][cc] = h; MrkL[r][cc] = bfr(vv - bff(h));
                    vv = (cc <= r) ? mrb[q] : 0.f; h = bfr(vv);
                    MrbH[r][cc] = h; MrbL[r][cc] = bfr(vv - bff(h));
                }
            }
        } else {
            s16x8 am0 = fragT(buf, 0, mi * 16, 0), am1 = fragT(buf, 0, mi * 16, 32);
            s16x8 sh0 = fragS(Shi, 0), sh1 = fragS(Shi, 32);
            s16x8 sl0 = fragS(Slo, 0), sl1 = fragS(Slo, 32);
            s16x8 vt0 = frag42(VT, 0);
            s16x8 lmh = *reinterpret_cast<const s16x8*>(&stMh[buf][mi * 16 + lr][lq * 8]);
            s16x8 lml = *reinterpret_cast<const s16x8*>(&stMl[buf][mi * 16 + lr][lq * 8]);
            f32x4v sat = MF(sl1, am1, MF(sl0, am0, MF(sh1, am1, MF(sh0, am0, z4))));
            sat = MF(vt0, lml, MF(vt0, lmh, sat));
#pragma unroll
            for (int q = 0; q < 4; q++) {
                const int r = lq * 4 + q, cc = mi * 16 + lr;
                unsigned short h = bfr(sat[q]);
                SATh[r][cc] = h;
                SATl[r][cc] = bfr(sat[q] - bff(h));
            }
        }
        __syncthreads();
        // ---- ph2 ----
        if (ni == 0) {
            s16x8 vt0 = frag42(VT, 0);
            oac = MF(frag42(MrkL, mi * 16), vt0,
                     MF(frag42(MrkH, mi * 16), vt0, oac));
            s16x8 sath = frag42(SATh, 0), satl = frag42(SATl, 0);
            s16x8 rbh = frag42(MrbH, mi * 16), rbl = frag42(MrbL, mi * 16);
            oac = MF(rbl, sath, MF(rbh, satl, MF(rbh, sath, oac)));
#pragma unroll
            for (int q = 0; q < 4; q++) {
                const int t = c * CCH + mi * 16 + lq * 4 + q;
                Ob16[rowoff + (size_t)t * HID + vq * 16 + lr] = bfr(oac[q]);
            }
        }
        {
            s16x8 sath = frag42(SATh, 0), satl = frag42(SATl, 0);
            s16x8 btf = frag42(BtT, w * 16);
            s16x8 ktf = frag42(KtT, w * 16);
            s16x8 vta = frag42(VT, 0);
            const float ed = stEd[buf][w * 16 + lr];
            Sacc = MF(sath, btf, Sacc);
            Sacc = MF(satl, btf, Sacc);
            Sacc = MF(vta, ktf, Sacc);
#pragma unroll
            for (int q = 0; q < 4; q++) {
                Sacc[q] *= ed;
                unsigned short h = bfr(Sacc[q]);
                Shi[lq * 4 + q][w * 16 + lr] = h;
                Slo[lq * 4 + q][w * 16 + lr] = bfr(Sacc[q] - bff(h));
            }
        }
        asm volatile("s_waitcnt vmcnt(0)" ::: "memory");
        __syncthreads();
        buf ^= 1;
    }
}

// ---------------------------------------------------------------------------
// stats (unchanged): per (row, head) mu, rsqrt -> MS (= dead Ed region).
// ---------------------------------------------------------------------------
__global__ __launch_bounds__(256) void stats_kernel(
        const unsigned short* __restrict__ O16, float* __restrict__ MS) {
    const int row = blockIdx.x;
    const int tid = threadIdx.x;
    const int c = tid * 4;
    ushort4 ou = *reinterpret_cast<const ushort4*>(O16 + (size_t)row * HID + c);
    float o[4] = {bff(ou.x), bff(ou.y), bff(ou.z), bff(ou.w)};
    float s1 = o[0] + o[1] + o[2] + o[3];
    float s2 = o[0]*o[0] + o[1]*o[1] + o[2]*o[2] + o[3]*o[3];
#pragma unroll
    for (int m = 1; m < 16; m <<= 1) {
        s1 += __shfl_xor(s1, m); s2 += __shfl_xor(s2, m);
    }
    if ((tid & 15) == 0) {
        const int hh = tid >> 4;
        const float mu = s1 * (1.0f / 64.0f);
        const float var = s2 * (1.0f / 64.0f) - mu * mu;
        float2 v; v.x = mu; v.y = rsqrtf(var + GN_EPS);
        *reinterpret_cast<float2*>(MS + (size_t)row * 32 + hh * 2) = v;
    }
}

// ---------------------------------------------------------------------------
// wogemm (unchanged): out = y @ W_o^T with fused y-compute in A-staging.
// ---------------------------------------------------------------------------
__global__ __launch_bounds__(256) void wogemm_kernel(
        const unsigned short* __restrict__ O16, const unsigned short* __restrict__ V16,
        const unsigned short* __restrict__ G16, const float* __restrict__ SB,
        const float* __restrict__ MS, const float* __restrict__ gnw,
        const float* __restrict__ gnb, const unsigned short* __restrict__ Wo,
        float* __restrict__ out) {
    __shared__ __align__(16) unsigned short As[128 * 32];
    __shared__ __align__(16) unsigned short Bs[128 * 32];
    const int tid = threadIdx.x;
    const int w = tid >> 6, l = tid & 63;
    const int bm = blockIdx.x * 128, bn = blockIdx.y * 128;
    const int wm = w >> 1, wn = w & 1;
    const int lr = l & 15, lk = (l >> 4) * 8;

    f32x4v acc[4][4];
#pragma unroll
    for (int i = 0; i < 4; i++)
#pragma unroll
        for (int j = 0; j < 4; j++)
#pragma unroll
            for (int q = 0; q < 4; q++) acc[i][j][q] = 0.f;

    for (int k0 = 0; k0 < HID; k0 += 32) {
#pragma unroll
        for (int c = 0; c < 2; c++) {
            int idx = c * 256 + tid;
            int row = idx >> 2, kp = (idx & 3) * 8;
            const int gr = bm + row;
            const size_t rb = (size_t)gr * HID + k0 + kp;
            uint4 ou = *reinterpret_cast<const uint4*>(O16 + rb);
            uint4 vu = *reinterpret_cast<const uint4*>(V16 + rb);
            uint4 gu = *reinterpret_cast<const uint4*>(G16 + rb);
            float o8[8], v8[8], g8[8];
            up8(ou, o8); up8(vu, v8); up8(gu, g8);
            const int hh = (k0 + kp) >> 6;
            float2 ms = *reinterpret_cast<const float2*>(MS + (size_t)gr * 32 + hh * 2);
            const float s3 = SB[((size_t)(gr >> 11) * 16 + hh) * TSEQ + (gr & (TSEQ - 1))];
            float4 w0 = ld4(gnw + k0 + kp), w1 = ld4(gnw + k0 + kp + 4);
            float4 b0 = ld4(gnb + k0 + kp), b1 = ld4(gnb + k0 + kp + 4);
            float wn8[8] = {w0.x, w0.y, w0.z, w0.w, w1.x, w1.y, w1.z, w1.w};
            float bn8[8] = {b0.x, b0.y, b0.z, b0.w, b1.x, b1.y, b1.z, b1.w};
            float y[8];
#pragma unroll
            for (int e = 0; e < 8; e++)
                y[e] = (fmaf((o8[e] - ms.x) * ms.y, wn8[e], bn8[e]) + s3 * v8[e]) * g8[e];
            uint4 u;
            u.x = pk2(y[0], y[1]); u.y = pk2(y[2], y[3]);
            u.z = pk2(y[4], y[5]); u.w = pk2(y[6], y[7]);
            *reinterpret_cast<uint4*>(&As[idx * 8]) = u;
        }
#pragma unroll
        for (int c = 0; c < 2; c++) {
            int idx = c * 256 + tid;
            int row = idx >> 2, kp = (idx & 3) * 8;
            gl16(Wo + (size_t)(bn + row) * HID + k0 + kp, &Bs[c * 2048 + w * 512]);
        }
        __syncthreads();
        s16x8 afx[4], bfx[4];
#pragma unroll
        for (int i = 0; i < 4; i++)
            afx[i] = *reinterpret_cast<const s16x8*>(&As[(wm * 64 + i * 16 + lr) * 32 + lk]);
#pragma unroll
        for (int j = 0; j < 4; j++)
            bfx[j] = *reinterpret_cast<const s16x8*>(&Bs[(wn * 64 + j * 16 + lr) * 32 + lk]);
#pragma unroll
        for (int i = 0; i < 4; i++)
#pragma unroll
            for (int j = 0; j < 4; j++)
                acc[i][j] = MF(afx[i], bfx[j], acc[i][j]);
        __syncthreads();
    }

#pragma unroll
    for (int i = 0; i < 4; i++) {
        const int grow0 = bm + wm * 64 + i * 16 + (l >> 4) * 4;
#pragma unroll
        for (int j = 0; j < 4; j++) {
            const int gcol = bn + wn * 64 + j * 16 + lr;
#pragma unroll
            for (int q = 0; q < 4; q++)
                out[(size_t)(grow0 + q) * HID + gcol] = acc[i][j][q];
        }
    }
}

// ---------------------------------------------------------------------------
extern "C" void kernel_launch(void* const* d_in, const int* in_sizes, int n_in,
                              void* d_out, int out_size, void* d_ws, size_t ws_size,
                              hipStream_t stream) {
    const float* x   = (const float*)d_in[0];
    const float* vf  = (const float*)d_in[1];
    const float* x_r = (const float*)d_in[2];
    const float* x_w = (const float*)d_in[3];
    const float* x_k = (const float*)d_in[4];
    const float* x_v = (const float*)d_in[5];
    const float* x_a = (const float*)d_in[6];
    const float* x_g = (const float*)d_in[7];
    const float* k_k = (const float*)d_in[8];
    const float* k_a = (const float*)d_in[9];
    const float* r_k = (const float*)d_in[10];
    const float* W_r = (const float*)d_in[11];
    const float* W_k = (const float*)d_in[12];
    const float* W_v = (const float*)d_in[13];
    const float* W_o = (const float*)d_in[14];
    const float* wA  = (const float*)d_in[15];
    const float* wB  = (const float*)d_in[16];
    const float* wb  = (const float*)d_in[17];
    const float* aA  = (const float*)d_in[18];
    const float* aB  = (const float*)d_in[19];
    const float* ab  = (const float*)d_in[20];
    const float* vA  = (const float*)d_in[21];
    const float* vB  = (const float*)d_in[22];
    const float* vb  = (const float*)d_in[23];
    const float* gA  = (const float*)d_in[24];
    const float* gB  = (const float*)d_in[25];
    const float* gnw = (const float*)d_in[26];
    const float* gnb = (const float*)d_in[27];
    float* out = (float*)d_out;

    float* ws = (float*)d_ws;
    const size_t SZ = (size_t)BTOT * HID;
    const size_t HH = (size_t)HID * HID;
    float*          REG  = ws;   // 64MB: [W16|O16 first 32MB][LM|G16 last 32MB]
    unsigned short* P    = (unsigned short*)(ws + SZ);
    unsigned short* R16  = P;
    unsigned short* K16  = P + 1 * SZ;
    unsigned short* V16  = P + 2 * SZ;
    unsigned short* A16  = P + 3 * SZ;
    unsigned short* KK16 = P + 4 * SZ;   // At -> AM (folded)
    unsigned short* H1   = P + 5 * SZ;               // [BTOT][352]
    unsigned short* WR   = H1 + (size_t)BTOT * L4N;
    unsigned short* Wr16 = WR;
    unsigned short* Wk16 = WR + 1 * HH;
    unsigned short* Wv16 = WR + 2 * HH;
    unsigned short* Wo16 = WR + 3 * HH;
    unsigned short* LW   = WR + 4 * HH;              // [352][1024]
    unsigned short* vB16 = LW + (size_t)L4N * HID;
    unsigned short* wB16 = vB16 + 65536;
    unsigned short* aB16 = wB16 + 65536;
    unsigned short* gB16 = aB16 + 65536;
    float*          SB   = (float*)(gB16 + 163840);  // [128][2048]
    float*          Ed   = SB + (size_t)128 * TSEQ;  // [128][64][64]
    float*          MS   = Ed;   // ALIAS: Ed dead after recchunk
    unsigned short* W16   = (unsigned short*)REG;          // decay (pre-cprep)
    unsigned short* O16   = (unsigned short*)REG;          // o (post-cprep)
    unsigned short* LMHp  = (unsigned short*)(REG + 8 * 1024 * 1024);
    unsigned short* LMLp  = LMHp + (size_t)128 * NCH * 1024;
    unsigned short* G16   = (unsigned short*)(REG + 8 * 1024 * 1024);  // post-rec

    const dim3 blk(256);
    const dim3 gBig(128, 8);
    const dim3 gP3(BTOT / 64, 8);
    const unsigned short* nu = nullptr;
    const float* np = nullptr;

    // --- single cast launch (prefix-offset table) ---
    CastArgs ca;
    const float* srcs[12] = {W_r, W_k, W_v, W_o, vA, wA, aA, gA, vB, wB, aB, gB};
    unsigned short* dsts[12] = {Wr16, Wk16, Wv16, Wo16,
                                LW, LW + 65536, LW + 131072, LW + 196608,
                                vB16, wB16, aB16, gB16};
    int cnts[12] = {(int)HH, (int)HH, (int)HH, (int)HH,
                    65536, 65536, 65536, 163840, 65536, 65536, 65536, 163840};
    int acc4 = 0;
    for (int s = 0; s < 12; s++) {
        ca.src[s] = srcs[s]; ca.dst[s] = dsts[s];
        ca.start4[s] = acc4;
        acc4 += cnts[s] / 4;
    }
    ca.start4[12] = acc4;
    cast_all_kernel<<<dim3((acc4 + 255) / 256), blk, 0, stream>>>(ca);

    // fused r, k, v0 projections
    proj3_kernel<<<gP3, blk, 0, stream>>>(
        x, x_r, x_k, x_v, Wr16, Wk16, Wv16, R16, K16, V16);
    // fused lora stage-1 (v,w,a,g) -> H1
    lora4_kernel<<<dim3(BTOT / 64), blk, 0, stream>>>(
        x, x_v, x_w, x_a, x_g, LW, H1);
    // v/w/a stage-2 in one launch
    stage2_kernel<<<dim3(128, 8, 3), blk, 0, stream>>>(
        H1, vB16, wB16, aB16, vb, wb, ab, V16, W16, A16, V16, vf);
    // fused prep + chunkprep + Minv + folded AM/LM
    cprep_kernel<<<dim3(128 * NCH), dim3(64), 0, stream>>>(
        K16, A16, R16, KK16, W16, k_k, k_a, r_k, SB, Ed, LMHp, LMLp);
    // chunked recurrence -> o bf16 (O16 over dead W16 region)
    recchunk_kernel<<<dim3(512), blk, 0, stream>>>(
        KK16, A16, K16, R16, V16, Ed, LMHp, LMLp, O16);
    // g = h_g @ gB^T (bf16, over dead LM region)
    mgemm<128,128,0,true><<<gBig, blk, 0, stream>>>(
        H1 + 192, gB16, G16, HID, 160, L4N, np, nu, np);
    // GroupNorm stats (MS over dead Ed region)
    stats_kernel<<<dim3(BTOT), blk, 0, stream>>>(O16, MS);
    // out = y @ W_o^T with fused y-compute
    wogemm_kernel<<<gBig, blk, 0, stream>>>(
        O16, V16, G16, SB, MS, gnw, gnb, Wo16, out);
    (void)in_sizes; (void)n_in; (void)out_size; (void)ws_size;
}

// Round 18
// 1195.418 us; speedup vs baseline: 1.0092x; 1.0092x over previous
//
#include <hip/hip_runtime.h>
#include <hip/hip_bf16.h>

// ---------------------------------------------------------------------------
// RWKV7 attention block — Round 18 (= R17 with cprep's AM/LM composes done
// via MFMA instead of scalar LDS loops: Minv stored hi/lo bf16, At^T and
// MakT staged in LDS; 28 MFMAs replace ~3K ds_reads per wave).
// 9 kernel launches.  B=8, T=2048, H=1024, NH=16. ws ~247.4 MB.
// ---------------------------------------------------------------------------

#define DEVI __device__ __forceinline__

constexpr int TSEQ = 2048;
constexpr int HID  = 1024;
constexpr int BTOT = 16384;   // B*T
constexpr int CCH  = 32;      // chunk length
constexpr int NCH  = TSEQ / CCH;
constexpr int L4N  = 352;     // combined lora hidden width
constexpr float W_SCALE = -0.6065306597126334f;
constexpr float GN_EPS  = 6.4e-4f;   // 64 * 1e-5

using s16x8  = __attribute__((ext_vector_type(8))) short;
using f32x4v = __attribute__((ext_vector_type(4))) float;

DEVI float4 ld4(const float* p) { return *reinterpret_cast<const float4*>(p); }
DEVI void   st4(float* p, float4 v) { *reinterpret_cast<float4*>(p) = v; }
DEVI float  sigf(float x) { return 1.0f / (1.0f + __expf(-x)); }
DEVI unsigned short bfr(float f) {
    unsigned int u = __float_as_uint(f);
    return (unsigned short)((u + 0x7fffu + ((u >> 16) & 1u)) >> 16);
}
DEVI float bff(unsigned short s) { return __uint_as_float(((unsigned int)s) << 16); }
DEVI unsigned int pk2(float lo, float hi) {
    return ((unsigned int)bfr(hi) << 16) | (unsigned int)bfr(lo);
}
DEVI void up8(uint4 u, float* f) {
    f[0]=bff((unsigned short)(u.x & 0xffffu)); f[1]=bff((unsigned short)(u.x >> 16));
    f[2]=bff((unsigned short)(u.y & 0xffffu)); f[3]=bff((unsigned short)(u.y >> 16));
    f[4]=bff((unsigned short)(u.z & 0xffffu)); f[5]=bff((unsigned short)(u.z >> 16));
    f[6]=bff((unsigned short)(u.w & 0xffffu)); f[7]=bff((unsigned short)(u.w >> 16));
}
DEVI f32x4v MF(s16x8 a, s16x8 b, f32x4v c) {
    return __builtin_amdgcn_mfma_f32_16x16x32_bf16(a, b, c, 0, 0, 0);
}
DEVI void gl16(const void* g, void* l) {
    __builtin_amdgcn_global_load_lds(
        (const __attribute__((address_space(1))) unsigned int*)g,
        (__attribute__((address_space(3))) unsigned int*)l, 16, 0, 0);
}
DEVI void gl4(const void* g, void* l) {
    __builtin_amdgcn_global_load_lds(
        (const __attribute__((address_space(1))) unsigned int*)g,
        (__attribute__((address_space(3))) unsigned int*)l, 4, 0, 0);
}

// ---------------------------------------------------------------------------
// cast_all: 12 f32->bf16 segments, prefix-offset table.
// ---------------------------------------------------------------------------
struct CastArgs {
    const float* src[12];
    unsigned short* dst[12];
    int start4[13];
};
__global__ __launch_bounds__(256) void cast_all_kernel(CastArgs a) {
    int i4 = blockIdx.x * 256 + threadIdx.x;
    if (i4 >= a.start4[12]) return;
    int seg = 0;
#pragma unroll
    for (int s = 1; s < 12; s++) seg += (i4 >= a.start4[s]) ? 1 : 0;
    int off = (i4 - a.start4[seg]) * 4;
    float4 v = ld4(a.src[seg] + off);
    ushort4 o; o.x = bfr(v.x); o.y = bfr(v.y); o.z = bfr(v.z); o.w = bfr(v.w);
    *reinterpret_cast<ushort4*>(a.dst[seg] + off) = o;
}

// ---------------------------------------------------------------------------
// proj3 (unchanged): fused r/k/v projections.
// ---------------------------------------------------------------------------
__global__ __launch_bounds__(256) void proj3_kernel(
        const float* __restrict__ x,
        const float* __restrict__ cr, const float* __restrict__ ck,
        const float* __restrict__ cv,
        const unsigned short* __restrict__ Wr, const unsigned short* __restrict__ Wk,
        const unsigned short* __restrict__ Wv,
        unsigned short* __restrict__ Ro, unsigned short* __restrict__ Ko,
        unsigned short* __restrict__ Vo) {
    __shared__ __align__(16) unsigned short As[3][64 * 32];
    __shared__ __align__(16) unsigned short Bs[3][128 * 32];
    const int tid = threadIdx.x;
    const int w = tid >> 6, l = tid & 63;
    const int bm = blockIdx.x * 64, bn = blockIdx.y * 128;
    const int wm = w >> 1, wn = w & 1;
    const int lr = l & 15, lq = l >> 4, lk = lq * 8;

    f32x4v acc[3][2][4];
#pragma unroll
    for (int p = 0; p < 3; p++)
#pragma unroll
        for (int i = 0; i < 2; i++)
#pragma unroll
            for (int j = 0; j < 4; j++)
#pragma unroll
                for (int q = 0; q < 4; q++) acc[p][i][j][q] = 0.f;

    const float* cvs[3] = {cr, ck, cv};
    const unsigned short* Ws[3] = {Wr, Wk, Wv};

    for (int k0 = 0; k0 < HID; k0 += 32) {
        {
            const int row = tid >> 2, kp = (tid & 3) * 8;
            const int gr = bm + row;
            const float* xp = x + (size_t)gr * HID + k0 + kp;
            float4 x0 = ld4(xp), x1 = ld4(xp + 4);
            float4 p0 = make_float4(0.f, 0.f, 0.f, 0.f), p1 = p0;
            if ((gr & (TSEQ - 1)) != 0) { p0 = ld4(xp - HID); p1 = ld4(xp - HID + 4); }
            float xb[8] = {x0.x, x0.y, x0.z, x0.w, x1.x, x1.y, x1.z, x1.w};
            float dx[8] = {p0.x - x0.x, p0.y - x0.y, p0.z - x0.z, p0.w - x0.w,
                           p1.x - x1.x, p1.y - x1.y, p1.z - x1.z, p1.w - x1.w};
#pragma unroll
            for (int p = 0; p < 3; p++) {
                float4 c0 = ld4(cvs[p] + k0 + kp), c1 = ld4(cvs[p] + k0 + kp + 4);
                float cc[8] = {c0.x, c0.y, c0.z, c0.w, c1.x, c1.y, c1.z, c1.w};
                uint4 u;
                u.x = pk2(fmaf(dx[0], cc[0], xb[0]), fmaf(dx[1], cc[1], xb[1]));
                u.y = pk2(fmaf(dx[2], cc[2], xb[2]), fmaf(dx[3], cc[3], xb[3]));
                u.z = pk2(fmaf(dx[4], cc[4], xb[4]), fmaf(dx[5], cc[5], xb[5]));
                u.w = pk2(fmaf(dx[6], cc[6], xb[6]), fmaf(dx[7], cc[7], xb[7]));
                *reinterpret_cast<uint4*>(&As[p][row * 32 + kp]) = u;
            }
        }
#pragma unroll
        for (int p = 0; p < 3; p++)
#pragma unroll
            for (int c = 0; c < 2; c++) {
                int idx = c * 256 + tid;
                int rw = idx >> 2, kp2 = (idx & 3) * 8;
                gl16(Ws[p] + (size_t)(bn + rw) * HID + k0 + kp2,
                     &Bs[p][c * 2048 + w * 512]);
            }
        __syncthreads();
#pragma unroll
        for (int p = 0; p < 3; p++) {
            s16x8 af[2], bf4[4];
#pragma unroll
            for (int i = 0; i < 2; i++)
                af[i] = *reinterpret_cast<const s16x8*>(
                    &As[p][(wm * 32 + i * 16 + lr) * 32 + lk]);
#pragma unroll
            for (int j = 0; j < 4; j++)
                bf4[j] = *reinterpret_cast<const s16x8*>(
                    &Bs[p][(wn * 64 + j * 16 + lr) * 32 + lk]);
#pragma unroll
            for (int i = 0; i < 2; i++)
#pragma unroll
                for (int j = 0; j < 4; j++)
                    acc[p][i][j] = MF(af[i], bf4[j], acc[p][i][j]);
        }
        __syncthreads();
    }

    unsigned short* dsts[3] = {Ro, Ko, Vo};
#pragma unroll
    for (int p = 0; p < 3; p++)
#pragma unroll
        for (int i = 0; i < 2; i++)
#pragma unroll
            for (int j = 0; j < 4; j++)
#pragma unroll
                for (int q = 0; q < 4; q++) {
                    const int grow = bm + wm * 32 + i * 16 + lq * 4 + q;
                    const int gcol = bn + wn * 64 + j * 16 + lr;
                    dsts[p][(size_t)grow * HID + gcol] = bfr(acc[p][i][j][q]);
                }
}

// ---------------------------------------------------------------------------
// lora4 (unchanged): fused v/w/a/g lora stage-1 -> H1[BTOT][352].
// ---------------------------------------------------------------------------
__global__ __launch_bounds__(256) void lora4_kernel(
        const float* __restrict__ x,
        const float* __restrict__ cv_, const float* __restrict__ cw_,
        const float* __restrict__ ca_, const float* __restrict__ cg_,
        const unsigned short* __restrict__ LW, unsigned short* __restrict__ H1) {
    __shared__ __align__(16) unsigned short As[4][64 * 32];
    __shared__ __align__(16) unsigned short Bs[L4N * 32];
    const int tid = threadIdx.x;
    const int w = tid >> 6, l = tid & 63;
    const int lr = l & 15, lq = l >> 4, lk = lq * 8;
    const int bm = blockIdx.x * 64;
    const float* cvs[4] = {cv_, cw_, ca_, cg_};

    f32x4v acc[22];
#pragma unroll
    for (int j = 0; j < 22; j++)
#pragma unroll
        for (int q = 0; q < 4; q++) acc[j][q] = 0.f;

    for (int k0 = 0; k0 < HID; k0 += 32) {
        {
            const int row = tid >> 2, kp = (tid & 3) * 8;
            const int gr = bm + row;
            const float* xp = x + (size_t)gr * HID + k0 + kp;
            float4 x0 = ld4(xp), x1 = ld4(xp + 4);
            float4 p0 = make_float4(0.f, 0.f, 0.f, 0.f), p1 = p0;
            if ((gr & (TSEQ - 1)) != 0) { p0 = ld4(xp - HID); p1 = ld4(xp - HID + 4); }
            float xb[8] = {x0.x, x0.y, x0.z, x0.w, x1.x, x1.y, x1.z, x1.w};
            float dx[8] = {p0.x - x0.x, p0.y - x0.y, p0.z - x0.z, p0.w - x0.w,
                           p1.x - x1.x, p1.y - x1.y, p1.z - x1.z, p1.w - x1.w};
#pragma unroll
            for (int p = 0; p < 4; p++) {
                float4 c0 = ld4(cvs[p] + k0 + kp), c1 = ld4(cvs[p] + k0 + kp + 4);
                float cc[8] = {c0.x, c0.y, c0.z, c0.w, c1.x, c1.y, c1.z, c1.w};
                uint4 u;
                u.x = pk2(fmaf(dx[0], cc[0], xb[0]), fmaf(dx[1], cc[1], xb[1]));
                u.y = pk2(fmaf(dx[2], cc[2], xb[2]), fmaf(dx[3], cc[3], xb[3]));
                u.z = pk2(fmaf(dx[4], cc[4], xb[4]), fmaf(dx[5], cc[5], xb[5]));
                u.w = pk2(fmaf(dx[6], cc[6], xb[6]), fmaf(dx[7], cc[7], xb[7]));
                *reinterpret_cast<uint4*>(&As[p][row * 32 + kp]) = u;
            }
        }
#pragma unroll
        for (int c = 0; c < 6; c++) {
            int idx = c * 256 + tid;
            if (idx < L4N * 4) {
                gl16(LW + (size_t)(idx >> 2) * HID + (idx & 3) * 8 + k0,
                     (char*)&Bs[0] + (c * 256 + w * 64) * 16);
            }
        }
        __syncthreads();
        s16x8 af[4];
#pragma unroll
        for (int p = 0; p < 4; p++)
            af[p] = *reinterpret_cast<const s16x8*>(&As[p][(w * 16 + lr) * 32 + lk]);
#pragma unroll
        for (int j = 0; j < 22; j++) {
            const int grp = (j < 4) ? 0 : (j < 8) ? 1 : (j < 12) ? 2 : 3;
            s16x8 bf = *reinterpret_cast<const s16x8*>(&Bs[(j * 16 + lr) * 32 + lk]);
            acc[j] = MF(af[grp], bf, acc[j]);
        }
        __syncthreads();
    }

#pragma unroll
    for (int j = 0; j < 22; j++)
#pragma unroll
        for (int q = 0; q < 4; q++) {
            const int grow = bm + w * 16 + lq * 4 + q;
            const int gcol = j * 16 + lr;
            float d = acc[j][q];
            if (j >= 4 && j < 8) d = tanhf(d);
            else if (j >= 12) d = sigf(d);
            H1[(size_t)grow * L4N + gcol] = bfr(d);
        }
}

// ---------------------------------------------------------------------------
// stage2 (unchanged): v/w/a lora stage-2 in one launch (blockIdx.z).
// ---------------------------------------------------------------------------
__global__ __launch_bounds__(256) void stage2_kernel(
        const unsigned short* __restrict__ H1,
        const unsigned short* __restrict__ vB16, const unsigned short* __restrict__ wB16,
        const unsigned short* __restrict__ aB16,
        const float* __restrict__ vb, const float* __restrict__ wb,
        const float* __restrict__ ab,
        unsigned short* __restrict__ Vout, unsigned short* __restrict__ Wout,
        unsigned short* __restrict__ Aout,
        const unsigned short* __restrict__ aux1, const float* __restrict__ aux2) {
    const int z = blockIdx.z;
    const unsigned short* Bw = (z == 0) ? vB16 : (z == 1) ? wB16 : aB16;
    const float* bias = (z == 0) ? vb : (z == 1) ? wb : ab;
    unsigned short* Cout = (z == 0) ? Vout : (z == 1) ? Wout : Aout;
    const int aoff = z * 64;
    __shared__ __align__(16) unsigned short As[128 * 32];
    __shared__ __align__(16) unsigned short Bs[128 * 32];
    const int tid = threadIdx.x;
    const int w = tid >> 6, l = tid & 63;
    const int bm = blockIdx.x * 128, bn = blockIdx.y * 128;
    const int wm = w >> 1, wn = w & 1;
    const int lr = l & 15, lk = (l >> 4) * 8;

    f32x4v acc[4][4];
#pragma unroll
    for (int i = 0; i < 4; i++)
#pragma unroll
        for (int j = 0; j < 4; j++)
#pragma unroll
            for (int q = 0; q < 4; q++) acc[i][j][q] = 0.f;

    for (int k0 = 0; k0 < 64; k0 += 32) {
#pragma unroll
        for (int c = 0; c < 2; c++) {
            int idx = c * 256 + tid;
            int row = idx >> 2, kp = (idx & 3) * 8;
            gl16(H1 + (size_t)(bm + row) * L4N + aoff + k0 + kp,
                 &As[c * 2048 + w * 512]);
        }
#pragma unroll
        for (int c = 0; c < 2; c++) {
            int idx = c * 256 + tid;
            int row = idx >> 2, kp = (idx & 3) * 8;
            gl16(Bw + (size_t)(bn + row) * 64 + k0 + kp, &Bs[c * 2048 + w * 512]);
        }
        __syncthreads();
        s16x8 afx[4], bfx[4];
#pragma unroll
        for (int i = 0; i < 4; i++)
            afx[i] = *reinterpret_cast<const s16x8*>(&As[(wm * 64 + i * 16 + lr) * 32 + lk]);
#pragma unroll
        for (int j = 0; j < 4; j++)
            bfx[j] = *reinterpret_cast<const s16x8*>(&Bs[(wn * 64 + j * 16 + lr) * 32 + lk]);
#pragma unroll
        for (int i = 0; i < 4; i++)
#pragma unroll
            for (int j = 0; j < 4; j++)
                acc[i][j] = MF(afx[i], bfx[j], acc[i][j]);
        __syncthreads();
    }

#pragma unroll
    for (int i = 0; i < 4; i++) {
        const int grow0 = bm + wm * 64 + i * 16 + (l >> 4) * 4;
#pragma unroll
        for (int j = 0; j < 4; j++) {
            const int gcol = bn + wn * 64 + j * 16 + lr;
            const float bsv = bias[gcol];
#pragma unroll
            for (int q = 0; q < 4; q++) {
                const int grow = grow0 + q;
                float d = acc[i][j][q];
                if (z == 0) {
                    float v0 = bff(aux1[(size_t)grow * HID + gcol]);
                    d = fmaf(aux2[(size_t)grow * HID + gcol] - v0, sigf(d + bsv), v0);
                } else if (z == 1) {
                    d = W_SCALE * sigf(d + bsv);
                } else {
                    d = sigf(d + bsv);
                }
                Cout[(size_t)grow * HID + gcol] = bfr(d);
            }
        }
    }
}

// ---------------------------------------------------------------------------
// mgemm (unchanged; the g stage-2).
// ---------------------------------------------------------------------------
template<int BM, int BN, int MODE, bool OUTBF>
__global__ __launch_bounds__(256) void mgemm(
        const unsigned short* __restrict__ Ab, const unsigned short* __restrict__ Bw,
        void* Cout, int N, int K, int lda,
        const float* __restrict__ bias,
        const unsigned short* aux1, const float* __restrict__ aux2) {
    constexpr int BK = 32;
    constexpr int WM_ = (BN == 128) ? 2 : 4;
    constexpr int WN_ = (BN == 128) ? 2 : 1;
    constexpr int WTM = BM / WM_, WTN = BN / WN_;
    constexpr int MF_ = WTM / 16, NF = WTN / 16;
    constexpr int ACALLS = (BM * BK) / 2048;
    constexpr int BCALLS = (BN * BK) / 2048;
    __shared__ __align__(16) unsigned short As[BM * BK];
    __shared__ __align__(16) unsigned short Bs[BN * BK];
    const int tid = threadIdx.x;
    const int w = tid >> 6, l = tid & 63;
    const int bm = blockIdx.x * BM, bn = blockIdx.y * BN;
    const int wm = w / WN_, wn = w % WN_;
    const int lr = l & 15, lk = (l >> 4) * 8;

    f32x4v acc[MF_][NF];
#pragma unroll
    for (int i = 0; i < MF_; i++)
#pragma unroll
        for (int j = 0; j < NF; j++)
#pragma unroll
            for (int q = 0; q < 4; q++) acc[i][j][q] = 0.f;

    for (int k0 = 0; k0 < K; k0 += BK) {
#pragma unroll
        for (int c = 0; c < ACALLS; c++) {
            int idx = c * 256 + tid;
            int row = idx >> 2, kp = (idx & 3) * 8;
            gl16(Ab + (size_t)(bm + row) * lda + k0 + kp, &As[c * 2048 + w * 512]);
        }
#pragma unroll
        for (int c = 0; c < BCALLS; c++) {
            int idx = c * 256 + tid;
            int row = idx >> 2, kp = (idx & 3) * 8;
            int gc = bn + row; if (gc > N - 1) gc = N - 1;
            gl16(Bw + (size_t)gc * K + k0 + kp, &Bs[c * 2048 + w * 512]);
        }
        __syncthreads();
        s16x8 afx[MF_], bfx[NF];
#pragma unroll
        for (int i = 0; i < MF_; i++)
            afx[i] = *reinterpret_cast<const s16x8*>(&As[(wm * WTM + i * 16 + lr) * BK + lk]);
#pragma unroll
        for (int j = 0; j < NF; j++)
            bfx[j] = *reinterpret_cast<const s16x8*>(&Bs[(wn * WTN + j * 16 + lr) * BK + lk]);
#pragma unroll
        for (int i = 0; i < MF_; i++)
#pragma unroll
            for (int j = 0; j < NF; j++)
                acc[i][j] = __builtin_amdgcn_mfma_f32_16x16x32_bf16(
                    afx[i], bfx[j], acc[i][j], 0, 0, 0);
        __syncthreads();
    }

#pragma unroll
    for (int i = 0; i < MF_; i++) {
        const int grow0 = bm + wm * WTM + i * 16 + (l >> 4) * 4;
#pragma unroll
        for (int j = 0; j < NF; j++) {
            const int gcol = bn + wn * WTN + j * 16 + lr;
            if (gcol >= N) continue;
#pragma unroll
            for (int q = 0; q < 4; q++) {
                const int grow = grow0 + q;
                float d = acc[i][j][q];
                if (OUTBF) ((unsigned short*)Cout)[(size_t)grow * N + gcol] = bfr(d);
                else       ((float*)Cout)[(size_t)grow * N + gcol] = d;
            }
        }
    }
}

// ---------------------------------------------------------------------------
// cprep v3: prep + chunkprep + Minv + folded AM/LM via MFMA.
//   row loop: scaling (At also -> AtT LDS), s3, Ed.
//   Mab f32 (masked); MakT hi/lo (masked, TRANSPOSED store).
//   fsub -> MnvH/L (hi/lo bf16).
//   AM = Mnv@At via MFMA (A=Mnv hi/lo, B=AtT) -> bf16 KK16.
//   LM = Mnv@Mak via MFMA (B=MakT hi/lo) -> hi/lo global.
// ---------------------------------------------------------------------------
__global__ __launch_bounds__(64) void cprep_kernel(
        unsigned short* __restrict__ K16, unsigned short* __restrict__ A16,
        unsigned short* __restrict__ R16, unsigned short* __restrict__ KK16,
        const unsigned short* __restrict__ W16,
        const float* __restrict__ kkc, const float* __restrict__ kac,
        const float* __restrict__ rkw,
        float* __restrict__ SB, float* __restrict__ Ed,
        unsigned short* __restrict__ MvH, unsigned short* __restrict__ MvL) {
    __shared__ __align__(16) unsigned short sA[32][64], sB[32][64], sK[32][64];
    __shared__ __align__(16) unsigned short AtT[64][40];
    __shared__ __align__(16) float Mab[32][36];
    __shared__ __align__(16) unsigned short MnvH[32][40], MnvL[32][40];
    __shared__ __align__(16) unsigned short MakTH[32][40], MakTL[32][40];
    const int bid = blockIdx.x;
    const int bh = bid >> 6, ch = bid & 63;
    const int bb = bh >> 4, hh = bh & 15;
    const int l = threadIdx.x;
    const int chn = hh * 64 + l;
    const float kkcv = kkc[chn], kacv = kac[chn], rkv = rkw[chn];
    const size_t cbase = ((size_t)(bb * TSEQ) + ch * CCH) * HID + hh * 64;
    size_t off = cbase + l;
    float cw = 0.f, er = 1.f;
    for (int i = 0; i < CCH; i++, off += HID) {
        const float k = bff(K16[off]);
        const float a = bff(A16[off]);
        const float r = bff(R16[off]);
        const float wv = bff(W16[off]);
        const float kr = k * kkcv;
        float ss = kr * kr;
        ss += __shfl_xor(ss, 1);  ss += __shfl_xor(ss, 2);
        ss += __shfl_xor(ss, 4);  ss += __shfl_xor(ss, 8);
        ss += __shfl_xor(ss, 16); ss += __shfl_xor(ss, 32);
        const float inv = 1.0f / fmaxf(sqrtf(ss), 1e-12f);
        const float kk = kr * inv;
        const float b  = kk * a;
        const float kn = k * fmaf(a - 1.0f, kacv, 1.0f);
        float s3 = r * kn * rkv;
        s3 += __shfl_xor(s3, 1);  s3 += __shfl_xor(s3, 2);
        s3 += __shfl_xor(s3, 4);  s3 += __shfl_xor(s3, 8);
        s3 += __shfl_xor(s3, 16); s3 += __shfl_xor(s3, 32);
        if (l == 0) SB[(size_t)bh * TSEQ + ch * CCH + i] = s3;
        const float cwp = cw; cw += wv;
        const float ea = __expf(cwp), ei = __expf(-cw);
        er = __expf(cw);
        const unsigned short At = bfr(-kk * ea);
        const unsigned short Bt = bfr(b * ei);
        const unsigned short Kt = bfr(kn * ei);
        A16[off] = Bt;
        K16[off] = Kt;
        R16[off] = bfr(r * er);
        sA[i][l] = At; sB[i][l] = Bt; sK[i][l] = Kt;
        AtT[l][i] = At;
    }
    Ed[((size_t)bh * NCH + ch) * 64 + l] = er;
    __syncthreads();
    const int lr = l & 15, lq = l >> 4;
    f32x4v z4; z4[0] = z4[1] = z4[2] = z4[3] = 0.f;
#pragma unroll
    for (int mi = 0; mi < 2; mi++)
#pragma unroll
        for (int ni = 0; ni < 2; ni++) {
            s16x8 a0 = *reinterpret_cast<const s16x8*>(&sA[mi * 16 + lr][lq * 8]);
            s16x8 a1 = *reinterpret_cast<const s16x8*>(&sA[mi * 16 + lr][32 + lq * 8]);
            s16x8 b0 = *reinterpret_cast<const s16x8*>(&sB[ni * 16 + lr][lq * 8]);
            s16x8 b1 = *reinterpret_cast<const s16x8*>(&sB[ni * 16 + lr][32 + lq * 8]);
            s16x8 k0 = *reinterpret_cast<const s16x8*>(&sK[ni * 16 + lr][lq * 8]);
            s16x8 k1 = *reinterpret_cast<const s16x8*>(&sK[ni * 16 + lr][32 + lq * 8]);
            f32x4v m  = MF(a1, b1, MF(a0, b0, z4));
            f32x4v mk = MF(a1, k1, MF(a0, k0, z4));
#pragma unroll
            for (int q = 0; q < 4; q++) {
                int r = mi * 16 + lq * 4 + q, cc2 = ni * 16 + lr;
                Mab[r][cc2] = (cc2 < r) ? m[q] : 0.f;
                float vv = (cc2 < r) ? mk[q] : 0.f;
                unsigned short h = bfr(vv);
                MakTH[cc2][r] = h;                 // transposed store
                MakTL[cc2][r] = bfr(vv - bff(h));
            }
        }
    __syncthreads();
    // forward substitution -> Minv columns (lane j) -> hi/lo LDS
    const int j = l & 31;
    float m[32];
#pragma unroll
    for (int i = 0; i < 32; i++) m[i] = (i == j) ? 1.f : 0.f;
#pragma unroll
    for (int i = 1; i < 32; i++) {
        float p0 = 0.f, p1 = 0.f, p2 = 0.f, p3 = 0.f;
#pragma unroll
        for (int k4_ = 0; k4_ < 32; k4_ += 4) {
            if (k4_ >= i) break;
            float4 L4 = *reinterpret_cast<const float4*>(&Mab[i][k4_]);
            p0 = fmaf(L4.x, m[k4_ + 0], p0);
            if (k4_ + 1 < i) p1 = fmaf(L4.y, m[k4_ + 1], p1);
            if (k4_ + 2 < i) p2 = fmaf(L4.z, m[k4_ + 2], p2);
            if (k4_ + 3 < i) p3 = fmaf(L4.w, m[k4_ + 3], p3);
        }
        m[i] += (p0 + p1) + (p2 + p3);
    }
    if (l < 32) {
#pragma unroll
        for (int i = 0; i < 32; i++) {
            unsigned short h = bfr(m[i]);
            MnvH[i][j] = h;
            MnvL[i][j] = bfr(m[i] - bff(h));
        }
    }
    __syncthreads();
    // AM (MFMA) -> KK16 ; LM (MFMA) -> hi/lo global
    {
        unsigned short* dH = MvH + (size_t)(bh * NCH + ch) * 1024;
        unsigned short* dL = MvL + (size_t)(bh * NCH + ch) * 1024;
#pragma unroll
        for (int mi = 0; mi < 2; mi++) {
            s16x8 ah = *reinterpret_cast<const s16x8*>(&MnvH[mi * 16 + lr][lq * 8]);
            s16x8 al = *reinterpret_cast<const s16x8*>(&MnvL[mi * 16 + lr][lq * 8]);
#pragma unroll
            for (int n = 0; n < 4; n++) {
                s16x8 bt = *reinterpret_cast<const s16x8*>(&AtT[n * 16 + lr][lq * 8]);
                f32x4v am = MF(al, bt, MF(ah, bt, z4));
#pragma unroll
                for (int q = 0; q < 4; q++)
                    KK16[cbase + (size_t)(mi * 16 + lq * 4 + q) * HID + n * 16 + lr]
                        = bfr(am[q]);
            }
#pragma unroll
            for (int n = 0; n < 2; n++) {
                s16x8 mh = *reinterpret_cast<const s16x8*>(&MakTH[n * 16 + lr][lq * 8]);
                s16x8 ml = *reinterpret_cast<const s16x8*>(&MakTL[n * 16 + lr][lq * 8]);
                f32x4v lm = MF(ah, ml, MF(al, mh, MF(ah, mh, z4)));
#pragma unroll
                for (int q = 0; q < 4; q++) {
                    const int r = mi * 16 + lq * 4 + q, cc = n * 16 + lr;
                    unsigned short h = bfr(lm[q]);
                    dH[r * 32 + cc] = h;
                    dL[r * 32 + cc] = bfr(lm[q] - bff(h));
                }
            }
        }
    }
}

// ---------------------------------------------------------------------------
// Chunked recurrence v2 (unchanged R17): 2 compute phases / 3 barriers.
// ---------------------------------------------------------------------------
__global__ __launch_bounds__(256) void recchunk_kernel(
        const unsigned short* __restrict__ AMG, const unsigned short* __restrict__ BtG,
        const unsigned short* __restrict__ KtG, const unsigned short* __restrict__ RtG,
        const unsigned short* __restrict__ V16, const float* __restrict__ Ed,
        const unsigned short* __restrict__ LMH, const unsigned short* __restrict__ LML,
        unsigned short* __restrict__ Ob16) {
    __shared__ __align__(16) unsigned short stT[2][4][CCH][64];
    __shared__ __align__(16) unsigned short stMh[2][32][32], stMl[2][32][32];
    __shared__ __align__(16) unsigned short stV[2][CCH][16];
    __shared__ __align__(16) float stEd[2][64];
    __shared__ __align__(16) unsigned short Shi[16][74], Slo[16][74];
    __shared__ __align__(16) unsigned short BtT[64][42], KtT[64][42];
    __shared__ __align__(16) unsigned short VT[16][42];
    __shared__ __align__(16) unsigned short MrkH[32][42], MrkL[32][42];
    __shared__ __align__(16) unsigned short MrbH[32][42], MrbL[32][42];
    __shared__ __align__(16) unsigned short SATh[16][42], SATl[16][42];

    const int bid = blockIdx.x;
    const int vq = bid >> 7, bh = bid & 127;
    const int tid = threadIdx.x;
    const int w = tid >> 6, l = tid & 63;
    const int lr = l & 15, lq = l >> 4;
    const int bb = bh >> 4, hh = bh & 15;
    const size_t rowoff = ((size_t)bb * TSEQ) * HID + hh * 64;
    const int mi = w >> 1, ni = w & 1;

    const int r8 = l >> 3, ck = l & 7;
    const int swz8 = (ck ^ r8) * 8;

    auto STAGE = [&](int buf, int cn) {
        if (cn >= NCH) return;
        const size_t cb = rowoff + (size_t)(cn * CCH) * HID;
        const unsigned short* srcs[4] = {AMG, BtG, KtG, RtG};
        const unsigned short* T = srcs[w];
#pragma unroll
        for (int c = 0; c < 4; c++)
            gl16(T + cb + (size_t)(c * 8 + r8) * HID + swz8, &stT[buf][w][c * 8][0]);
        if (w == 0) {
            gl16(V16 + cb + (size_t)(l >> 1) * HID + vq * 16 + (l & 1) * 8,
                 &stV[buf][0][0]);
            gl4(Ed + ((size_t)bh * NCH + cn) * 64 + l, &stEd[buf][0]);
        } else if (w == 1) {
#pragma unroll
            for (int c = 0; c < 2; c++)
                gl16(LMH + (size_t)(bh * NCH + cn) * 1024 + c * 512 + l * 8,
                     (char*)&stMh[buf][0][0] + c * 1024);
        } else if (w == 2) {
#pragma unroll
            for (int c = 0; c < 2; c++)
                gl16(LML + (size_t)(bh * NCH + cn) * 1024 + c * 512 + l * 8,
                     (char*)&stMl[buf][0][0] + c * 1024);
        }
    };

    for (int idx = tid; idx < 16 * 74; idx += 256) {
        ((unsigned short*)Shi)[idx] = 0;
        ((unsigned short*)Slo)[idx] = 0;
    }
    STAGE(0, 0);
    asm volatile("s_waitcnt vmcnt(0)" ::: "memory");
    __syncthreads();

    auto fragT = [&](int bf, int tn, int rbase, int kb) -> s16x8 {
        int row = rbase + lr;
        int chv = ((kb >> 3) + lq) ^ (row & 7);
        return *reinterpret_cast<const s16x8*>(
            (const char*)&stT[bf][tn][0][0] + row * 128 + chv * 16);
    };
    auto fragS = [&](const unsigned short (*Sx)[74], int kb) -> s16x8 {
        return *reinterpret_cast<const s16x8*>(&Sx[lr][kb + lq * 8]);
    };
    auto frag42 = [&](const unsigned short (*T)[42], int rbase) -> s16x8 {
        return *reinterpret_cast<const s16x8*>(&T[rbase + lr][lq * 8]);
    };

    f32x4v Sacc;
#pragma unroll
    for (int q = 0; q < 4; q++) Sacc[q] = 0.f;
    f32x4v z4; z4[0] = z4[1] = z4[2] = z4[3] = 0.f;

    int buf = 0;
    for (int c = 0; c < NCH; c++) {
        STAGE(buf ^ 1, c + 1);
        {
            const int tt = tid & 31, g8 = tid >> 5;
            const int ch = g8 ^ (tt & 7);
            uint4 bu = *reinterpret_cast<const uint4*>(&stT[buf][1][tt][ch * 8]);
            uint4 ku = *reinterpret_cast<const uint4*>(&stT[buf][2][tt][ch * 8]);
            unsigned int bw[4] = {bu.x, bu.y, bu.z, bu.w};
            unsigned int kw[4] = {ku.x, ku.y, ku.z, ku.w};
#pragma unroll
            for (int e = 0; e < 4; e++) {
                BtT[g8 * 8 + 2 * e][tt]     = (unsigned short)(bw[e] & 0xffffu);
                BtT[g8 * 8 + 2 * e + 1][tt] = (unsigned short)(bw[e] >> 16);
                KtT[g8 * 8 + 2 * e][tt]     = (unsigned short)(kw[e] & 0xffffu);
                KtT[g8 * 8 + 2 * e + 1][tt] = (unsigned short)(kw[e] >> 16);
            }
            if (g8 < 4) {
                ushort4 vu = *reinterpret_cast<const ushort4*>(&stV[buf][tt][g8 * 4]);
                VT[g8 * 4 + 0][tt] = vu.x; VT[g8 * 4 + 1][tt] = vu.y;
                VT[g8 * 4 + 2][tt] = vu.z; VT[g8 * 4 + 3][tt] = vu.w;
            }
        }
        __syncthreads();
        f32x4v oac = z4;
        if (ni == 0) {
            s16x8 rt0 = fragT(buf, 3, mi * 16, 0), rt1 = fragT(buf, 3, mi * 16, 32);
            s16x8 sh0 = fragS(Shi, 0), sh1 = fragS(Shi, 32);
            s16x8 sl0 = fragS(Slo, 0), sl1 = fragS(Slo, 32);
            oac = MF(rt1, sl1, MF(rt0, sl0, MF(rt1, sh1, MF(rt0, sh0, z4))));
#pragma unroll
            for (int n = 0; n < 2; n++) {
                s16x8 kt0 = fragT(buf, 2, n * 16, 0), kt1 = fragT(buf, 2, n * 16, 32);
                s16x8 bt0 = fragT(buf, 1, n * 16, 0), bt1 = fragT(buf, 1, n * 16, 32);
                f32x4v mrk = MF(rt1, kt1, MF(rt0, kt0, z4));
                f32x4v mrb = MF(rt1, bt1, MF(rt0, bt0, z4));
#pragma unroll
                for (int q = 0; q < 4; q++) {
                    const int r = mi * 16 + lq * 4 + q, cc = n * 16 + lr;
                    float vv = (cc <= r) ? mrk[q] : 0.f;
                    unsigned short h = bfr(vv);
                    MrkH[r][cc] = h; MrkL[r][cc] = bfr(vv - bff(h));
                    vv = (cc <= r) ? mrb[q] : 0.f; h = bfr(vv);
                    MrbH[r][cc] = h; MrbL[r][cc] = bfr(vv - bff(h));
                }
            }
        } else {
            s16x8 am0 = fragT(buf, 0, mi * 16, 0), am1 = fragT(buf, 0, mi * 16, 32);
            s16x8 sh0 = fragS(Shi, 0), sh1 = fragS(Shi, 32);
            s16x8 sl0 = fragS(Slo, 0), sl1 = fragS(Slo, 32);
            s16x8 vt0 = frag42(VT, 0);
            s16x8 lmh = *reinterpret_cast<const s16x8*>(&stMh[buf][mi * 16 + lr][lq * 8]);
            s16x8 lml = *reinterpret_cast<const s16x8*>(&stMl[buf][mi * 16 + lr][lq * 8]);
            f32x4v sat = MF(sl1, am1, MF(sl0, am0, MF(sh1, am1, MF(sh0, am0, z4))));
            sat = MF(vt0, lml, MF(vt0, lmh, sat));
#pragma unroll
            for (int q = 0; q < 4; q++) {
                const int r = lq * 4 + q, cc = mi * 16 + lr;
                unsigned short h = bfr(sat[q]);
                SATh[r][cc] = h;
                SATl[r][cc] = bfr(sat[q] - bff(h));
            }
        }
        __syncthreads();
        if (ni == 0) {
            s16x8 vt0 = frag42(VT, 0);
            oac = MF(frag42(MrkL, mi * 16), vt0,
                     MF(frag42(MrkH, mi * 16), vt0, oac));
            s16x8 sath = frag42(SATh, 0), satl = frag42(SATl, 0);
            s16x8 rbh = frag42(MrbH, mi * 16), rbl = frag42(MrbL, mi * 16);
            oac = MF(rbl, sath, MF(rbh, satl, MF(rbh, sath, oac)));
#pragma unroll
            for (int q = 0; q < 4; q++) {
                const int t = c * CCH + mi * 16 + lq * 4 + q;
                Ob16[rowoff + (size_t)t * HID + vq * 16 + lr] = bfr(oac[q]);
            }
        }
        {
            s16x8 sath = frag42(SATh, 0), satl = frag42(SATl, 0);
            s16x8 btf = frag42(BtT, w * 16);
            s16x8 ktf = frag42(KtT, w * 16);
            s16x8 vta = frag42(VT, 0);
            const float ed = stEd[buf][w * 16 + lr];
            Sacc = MF(sath, btf, Sacc);
            Sacc = MF(satl, btf, Sacc);
            Sacc = MF(vta, ktf, Sacc);
#pragma unroll
            for (int q = 0; q < 4; q++) {
                Sacc[q] *= ed;
                unsigned short h = bfr(Sacc[q]);
                Shi[lq * 4 + q][w * 16 + lr] = h;
                Slo[lq * 4 + q][w * 16 + lr] = bfr(Sacc[q] - bff(h));
            }
        }
        asm volatile("s_waitcnt vmcnt(0)" ::: "memory");
        __syncthreads();
        buf ^= 1;
    }
}

// ---------------------------------------------------------------------------
// stats (unchanged): per (row, head) mu, rsqrt -> MS (= dead Ed region).
// ---------------------------------------------------------------------------
__global__ __launch_bounds__(256) void stats_kernel(
        const unsigned short* __restrict__ O16, float* __restrict__ MS) {
    const int row = blockIdx.x;
    const int tid = threadIdx.x;
    const int c = tid * 4;
    ushort4 ou = *reinterpret_cast<const ushort4*>(O16 + (size_t)row * HID + c);
    float o[4] = {bff(ou.x), bff(ou.y), bff(ou.z), bff(ou.w)};
    float s1 = o[0] + o[1] + o[2] + o[3];
    float s2 = o[0]*o[0] + o[1]*o[1] + o[2]*o[2] + o[3]*o[3];
#pragma unroll
    for (int m = 1; m < 16; m <<= 1) {
        s1 += __shfl_xor(s1, m); s2 += __shfl_xor(s2, m);
    }
    if ((tid & 15) == 0) {
        const int hh = tid >> 4;
        const float mu = s1 * (1.0f / 64.0f);
        const float var = s2 * (1.0f / 64.0f) - mu * mu;
        float2 v; v.x = mu; v.y = rsqrtf(var + GN_EPS);
        *reinterpret_cast<float2*>(MS + (size_t)row * 32 + hh * 2) = v;
    }
}

// ---------------------------------------------------------------------------
// wogemm (unchanged): out = y @ W_o^T with fused y-compute in A-staging.
// ---------------------------------------------------------------------------
__global__ __launch_bounds__(256) void wogemm_kernel(
        const unsigned short* __restrict__ O16, const unsigned short* __restrict__ V16,
        const unsigned short* __restrict__ G16, const float* __restrict__ SB,
        const float* __restrict__ MS, const float* __restrict__ gnw,
        const float* __restrict__ gnb, const unsigned short* __restrict__ Wo,
        float* __restrict__ out) {
    __shared__ __align__(16) unsigned short As[128 * 32];
    __shared__ __align__(16) unsigned short Bs[128 * 32];
    const int tid = threadIdx.x;
    const int w = tid >> 6, l = tid & 63;
    const int bm = blockIdx.x * 128, bn = blockIdx.y * 128;
    const int wm = w >> 1, wn = w & 1;
    const int lr = l & 15, lk = (l >> 4) * 8;

    f32x4v acc[4][4];
#pragma unroll
    for (int i = 0; i < 4; i++)
#pragma unroll
        for (int j = 0; j < 4; j++)
#pragma unroll
            for (int q = 0; q < 4; q++) acc[i][j][q] = 0.f;

    for (int k0 = 0; k0 < HID; k0 += 32) {
#pragma unroll
        for (int c = 0; c < 2; c++) {
            int idx = c * 256 + tid;
            int row = idx >> 2, kp = (idx & 3) * 8;
            const int gr = bm + row;
            const size_t rb = (size_t)gr * HID + k0 + kp;
            uint4 ou = *reinterpret_cast<const uint4*>(O16 + rb);
            uint4 vu = *reinterpret_cast<const uint4*>(V16 + rb);
            uint4 gu = *reinterpret_cast<const uint4*>(G16 + rb);
            float o8[8], v8[8], g8[8];
            up8(ou, o8); up8(vu, v8); up8(gu, g8);
            const int hh = (k0 + kp) >> 6;
            float2 ms = *reinterpret_cast<const float2*>(MS + (size_t)gr * 32 + hh * 2);
            const float s3 = SB[((size_t)(gr >> 11) * 16 + hh) * TSEQ + (gr & (TSEQ - 1))];
            float4 w0 = ld4(gnw + k0 + kp), w1 = ld4(gnw + k0 + kp + 4);
            float4 b0 = ld4(gnb + k0 + kp), b1 = ld4(gnb + k0 + kp + 4);
            float wn8[8] = {w0.x, w0.y, w0.z, w0.w, w1.x, w1.y, w1.z, w1.w};
            float bn8[8] = {b0.x, b0.y, b0.z, b0.w, b1.x, b1.y, b1.z, b1.w};
            float y[8];
#pragma unroll
            for (int e = 0; e < 8; e++)
                y[e] = (fmaf((o8[e] - ms.x) * ms.y, wn8[e], bn8[e]) + s3 * v8[e]) * g8[e];
            uint4 u;
            u.x = pk2(y[0], y[1]); u.y = pk2(y[2], y[3]);
            u.z = pk2(y[4], y[5]); u.w = pk2(y[6], y[7]);
            *reinterpret_cast<uint4*>(&As[idx * 8]) = u;
        }
#pragma unroll
        for (int c = 0; c < 2; c++) {
            int idx = c * 256 + tid;
            int row = idx >> 2, kp = (idx & 3) * 8;
            gl16(Wo + (size_t)(bn + row) * HID + k0 + kp, &Bs[c * 2048 + w * 512]);
        }
        __syncthreads();
        s16x8 afx[4], bfx[4];
#pragma unroll
        for (int i = 0; i < 4; i++)
            afx[i] = *reinterpret_cast<const s16x8*>(&As[(wm * 64 + i * 16 + lr) * 32 + lk]);
#pragma unroll
        for (int j = 0; j < 4; j++)
            bfx[j] = *reinterpret_cast<const s16x8*>(&Bs[(wn * 64 + j * 16 + lr) * 32 + lk]);
#pragma unroll
        for (int i = 0; i < 4; i++)
#pragma unroll
            for (int j = 0; j < 4; j++)
                acc[i][j] = MF(afx[i], bfx[j], acc[i][j]);
        __syncthreads();
    }

#pragma unroll
    for (int i = 0; i < 4; i++) {
        const int grow0 = bm + wm * 64 + i * 16 + (l >> 4) * 4;
#pragma unroll
        for (int j = 0; j < 4; j++) {
            const int gcol = bn + wn * 64 + j * 16 + lr;
#pragma unroll
            for (int q = 0; q < 4; q++)
                out[(size_t)(grow0 + q) * HID + gcol] = acc[i][j][q];
        }
    }
}

// ---------------------------------------------------------------------------
extern "C" void kernel_launch(void* const* d_in, const int* in_sizes, int n_in,
                              void* d_out, int out_size, void* d_ws, size_t ws_size,
                              hipStream_t stream) {
    const float* x   = (const float*)d_in[0];
    const float* vf  = (const float*)d_in[1];
    const float* x_r = (const float*)d_in[2];
    const float* x_w = (const float*)d_in[3];
    const float* x_k = (const float*)d_in[4];
    const float* x_v = (const float*)d_in[5];
    const float* x_a = (const float*)d_in[6];
    const float* x_g = (const float*)d_in[7];
    const float* k_k = (const float*)d_in[8];
    const float* k_a = (const float*)d_in[9];
    const float* r_k = (const float*)d_in[10];
    const float* W_r = (const float*)d_in[11];
    const float* W_k = (const float*)d_in[12];
    const float* W_v = (const float*)d_in[13];
    const float* W_o = (const float*)d_in[14];
    const float* wA  = (const float*)d_in[15];
    const float* wB  = (const float*)d_in[16];
    const float* wb  = (const float*)d_in[17];
    const float* aA  = (const float*)d_in[18];
    const float* aB  = (const float*)d_in[19];
    const float* ab  = (const float*)d_in[20];
    const float* vA  = (const float*)d_in[21];
    const float* vB  = (const float*)d_in[22];
    const float* vb  = (const float*)d_in[23];
    const float* gA  = (const float*)d_in[24];
    const float* gB  = (const float*)d_in[25];
    const float* gnw = (const float*)d_in[26];
    const float* gnb = (const float*)d_in[27];
    float* out = (float*)d_out;

    float* ws = (float*)d_ws;
    const size_t SZ = (size_t)BTOT * HID;
    const size_t HH = (size_t)HID * HID;
    float*          REG  = ws;   // 64MB: [W16|O16 first 32MB][LM|G16 last 32MB]
    unsigned short* P    = (unsigned short*)(ws + SZ);
    unsigned short* R16  = P;
    unsigned short* K16  = P + 1 * SZ;
    unsigned short* V16  = P + 2 * SZ;
    unsigned short* A16  = P + 3 * SZ;
    unsigned short* KK16 = P + 4 * SZ;   // AM (folded)
    unsigned short* H1   = P + 5 * SZ;               // [BTOT][352]
    unsigned short* WR   = H1 + (size_t)BTOT * L4N;
    unsigned short* Wr16 = WR;
    unsigned short* Wk16 = WR + 1 * HH;
    unsigned short* Wv16 = WR + 2 * HH;
    unsigned short* Wo16 = WR + 3 * HH;
    unsigned short* LW   = WR + 4 * HH;              // [352][1024]
    unsigned short* vB16 = LW + (size_t)L4N * HID;
    unsigned short* wB16 = vB16 + 65536;
    unsigned short* aB16 = wB16 + 65536;
    unsigned short* gB16 = aB16 + 65536;
    float*          SB   = (float*)(gB16 + 163840);  // [128][2048]
    float*          Ed   = SB + (size_t)128 * TSEQ;  // [128][64][64]
    float*          MS   = Ed;   // ALIAS: Ed dead after recchunk
    unsigned short* W16   = (unsigned short*)REG;          // decay (pre-cprep)
    unsigned short* O16   = (unsigned short*)REG;          // o (post-cprep)
    unsigned short* LMHp  = (unsigned short*)(REG + 8 * 1024 * 1024);
    unsigned short* LMLp  = LMHp + (size_t)128 * NCH * 1024;
    unsigned short* G16   = (unsigned short*)(REG + 8 * 1024 * 1024);  // post-rec

    const dim3 blk(256);
    const dim3 gBig(128, 8);
    const dim3 gP3(BTOT / 64, 8);
    const unsigned short* nu = nullptr;
    const float* np = nullptr;

    // --- single cast launch (prefix-offset table) ---
    CastArgs ca;
    const float* srcs[12] = {W_r, W_k, W_v, W_o, vA, wA, aA, gA, vB, wB, aB, gB};
    unsigned short* dsts[12] = {Wr16, Wk16, Wv16, Wo16,
                                LW, LW + 65536, LW + 131072, LW + 196608,
                                vB16, wB16, aB16, gB16};
    int cnts[12] = {(int)HH, (int)HH, (int)HH, (int)HH,
                    65536, 65536, 65536, 163840, 65536, 65536, 65536, 163840};
    int acc4 = 0;
    for (int s = 0; s < 12; s++) {
        ca.src[s] = srcs[s]; ca.dst[s] = dsts[s];
        ca.start4[s] = acc4;
        acc4 += cnts[s] / 4;
    }
    ca.start4[12] = acc4;
    cast_all_kernel<<<dim3((acc4 + 255) / 256), blk, 0, stream>>>(ca);

    // fused r, k, v0 projections
    proj3_kernel<<<gP3, blk, 0, stream>>>(
        x, x_r, x_k, x_v, Wr16, Wk16, Wv16, R16, K16, V16);
    // fused lora stage-1 (v,w,a,g) -> H1
    lora4_kernel<<<dim3(BTOT / 64), blk, 0, stream>>>(
        x, x_v, x_w, x_a, x_g, LW, H1);
    // v/w/a stage-2 in one launch
    stage2_kernel<<<dim3(128, 8, 3), blk, 0, stream>>>(
        H1, vB16, wB16, aB16, vb, wb, ab, V16, W16, A16, V16, vf);
    // fused prep + chunkprep + Minv + folded AM/LM (MFMA composes)
    cprep_kernel<<<dim3(128 * NCH), dim3(64), 0, stream>>>(
        K16, A16, R16, KK16, W16, k_k, k_a, r_k, SB, Ed, LMHp, LMLp);
    // chunked recurrence -> o bf16 (O16 over dead W16 region)
    recchunk_kernel<<<dim3(512), blk, 0, stream>>>(
        KK16, A16, K16, R16, V16, Ed, LMHp, LMLp, O16);
    // g = h_g @ gB^T (bf16, over dead LM region)
    mgemm<128,128,0,true><<<gBig, blk, 0, stream>>>(
        H1 + 192, gB16, G16, HID, 160, L4N, np, nu, np);
    // GroupNorm stats (MS over dead Ed region)
    stats_kernel<<<dim3(BTOT), blk, 0, stream>>>(O16, MS);
    // out = y @ W_o^T with fused y-compute
    wogemm_kernel<<<gBig, blk, 0, stream>>>(
        O16, V16, G16, SB, MS, gnw, gnb, Wo16, out);
    (void)in_sizes; (void)n_in; (void)out_size; (void)ws_size;
}

// Round 19
// 960.718 us; speedup vs baseline: 1.2557x; 1.2443x over previous
//
#include <hip/hip_runtime.h>
#include <hip/hip_bf16.h>

// ---------------------------------------------------------------------------
// RWKV7 attention block — Round 19 (= R18 with cprep split into
// zero-LDS rowprep [high occupancy for the serial prefix row loop] and a
// small compose kernel [Mab/Mak/Minv/AM/LM via MFMA, 19.5KB LDS]).
// 10 kernel launches.  B=8, T=2048, H=1024, NH=16. ws ~247.4 MB.
// ---------------------------------------------------------------------------

#define DEVI __device__ __forceinline__

constexpr int TSEQ = 2048;
constexpr int HID  = 1024;
constexpr int BTOT = 16384;   // B*T
constexpr int CCH  = 32;      // chunk length
constexpr int NCH  = TSEQ / CCH;
constexpr int L4N  = 352;     // combined lora hidden width
constexpr float W_SCALE = -0.6065306597126334f;
constexpr float GN_EPS  = 6.4e-4f;   // 64 * 1e-5

using s16x8  = __attribute__((ext_vector_type(8))) short;
using f32x4v = __attribute__((ext_vector_type(4))) float;

DEVI float4 ld4(const float* p) { return *reinterpret_cast<const float4*>(p); }
DEVI void   st4(float* p, float4 v) { *reinterpret_cast<float4*>(p) = v; }
DEVI float  sigf(float x) { return 1.0f / (1.0f + __expf(-x)); }
DEVI unsigned short bfr(float f) {
    unsigned int u = __float_as_uint(f);
    return (unsigned short)((u + 0x7fffu + ((u >> 16) & 1u)) >> 16);
}
DEVI float bff(unsigned short s) { return __uint_as_float(((unsigned int)s) << 16); }
DEVI unsigned int pk2(float lo, float hi) {
    return ((unsigned int)bfr(hi) << 16) | (unsigned int)bfr(lo);
}
DEVI void up8(uint4 u, float* f) {
    f[0]=bff((unsigned short)(u.x & 0xffffu)); f[1]=bff((unsigned short)(u.x >> 16));
    f[2]=bff((unsigned short)(u.y & 0xffffu)); f[3]=bff((unsigned short)(u.y >> 16));
    f[4]=bff((unsigned short)(u.z & 0xffffu)); f[5]=bff((unsigned short)(u.z >> 16));
    f[6]=bff((unsigned short)(u.w & 0xffffu)); f[7]=bff((unsigned short)(u.w >> 16));
}
DEVI f32x4v MF(s16x8 a, s16x8 b, f32x4v c) {
    return __builtin_amdgcn_mfma_f32_16x16x32_bf16(a, b, c, 0, 0, 0);
}
DEVI void gl16(const void* g, void* l) {
    __builtin_amdgcn_global_load_lds(
        (const __attribute__((address_space(1))) unsigned int*)g,
        (__attribute__((address_space(3))) unsigned int*)l, 16, 0, 0);
}
DEVI void gl4(const void* g, void* l) {
    __builtin_amdgcn_global_load_lds(
        (const __attribute__((address_space(1))) unsigned int*)g,
        (__attribute__((address_space(3))) unsigned int*)l, 4, 0, 0);
}

// ---------------------------------------------------------------------------
// cast_all: 12 f32->bf16 segments, prefix-offset table.
// ---------------------------------------------------------------------------
struct CastArgs {
    const float* src[12];
    unsigned short* dst[12];
    int start4[13];
};
__global__ __launch_bounds__(256) void cast_all_kernel(CastArgs a) {
    int i4 = blockIdx.x * 256 + threadIdx.x;
    if (i4 >= a.start4[12]) return;
    int seg = 0;
#pragma unroll
    for (int s = 1; s < 12; s++) seg += (i4 >= a.start4[s]) ? 1 : 0;
    int off = (i4 - a.start4[seg]) * 4;
    float4 v = ld4(a.src[seg] + off);
    ushort4 o; o.x = bfr(v.x); o.y = bfr(v.y); o.z = bfr(v.z); o.w = bfr(v.w);
    *reinterpret_cast<ushort4*>(a.dst[seg] + off) = o;
}

// ---------------------------------------------------------------------------
// proj3 (unchanged): fused r/k/v projections.
// ---------------------------------------------------------------------------
__global__ __launch_bounds__(256) void proj3_kernel(
        const float* __restrict__ x,
        const float* __restrict__ cr, const float* __restrict__ ck,
        const float* __restrict__ cv,
        const unsigned short* __restrict__ Wr, const unsigned short* __restrict__ Wk,
        const unsigned short* __restrict__ Wv,
        unsigned short* __restrict__ Ro, unsigned short* __restrict__ Ko,
        unsigned short* __restrict__ Vo) {
    __shared__ __align__(16) unsigned short As[3][64 * 32];
    __shared__ __align__(16) unsigned short Bs[3][128 * 32];
    const int tid = threadIdx.x;
    const int w = tid >> 6, l = tid & 63;
    const int bm = blockIdx.x * 64, bn = blockIdx.y * 128;
    const int wm = w >> 1, wn = w & 1;
    const int lr = l & 15, lq = l >> 4, lk = lq * 8;

    f32x4v acc[3][2][4];
#pragma unroll
    for (int p = 0; p < 3; p++)
#pragma unroll
        for (int i = 0; i < 2; i++)
#pragma unroll
            for (int j = 0; j < 4; j++)
#pragma unroll
                for (int q = 0; q < 4; q++) acc[p][i][j][q] = 0.f;

    const float* cvs[3] = {cr, ck, cv};
    const unsigned short* Ws[3] = {Wr, Wk, Wv};

    for (int k0 = 0; k0 < HID; k0 += 32) {
        {
            const int row = tid >> 2, kp = (tid & 3) * 8;
            const int gr = bm + row;
            const float* xp = x + (size_t)gr * HID + k0 + kp;
            float4 x0 = ld4(xp), x1 = ld4(xp + 4);
            float4 p0 = make_float4(0.f, 0.f, 0.f, 0.f), p1 = p0;
            if ((gr & (TSEQ - 1)) != 0) { p0 = ld4(xp - HID); p1 = ld4(xp - HID + 4); }
            float xb[8] = {x0.x, x0.y, x0.z, x0.w, x1.x, x1.y, x1.z, x1.w};
            float dx[8] = {p0.x - x0.x, p0.y - x0.y, p0.z - x0.z, p0.w - x0.w,
                           p1.x - x1.x, p1.y - x1.y, p1.z - x1.z, p1.w - x1.w};
#pragma unroll
            for (int p = 0; p < 3; p++) {
                float4 c0 = ld4(cvs[p] + k0 + kp), c1 = ld4(cvs[p] + k0 + kp + 4);
                float cc[8] = {c0.x, c0.y, c0.z, c0.w, c1.x, c1.y, c1.z, c1.w};
                uint4 u;
                u.x = pk2(fmaf(dx[0], cc[0], xb[0]), fmaf(dx[1], cc[1], xb[1]));
                u.y = pk2(fmaf(dx[2], cc[2], xb[2]), fmaf(dx[3], cc[3], xb[3]));
                u.z = pk2(fmaf(dx[4], cc[4], xb[4]), fmaf(dx[5], cc[5], xb[5]));
                u.w = pk2(fmaf(dx[6], cc[6], xb[6]), fmaf(dx[7], cc[7], xb[7]));
                *reinterpret_cast<uint4*>(&As[p][row * 32 + kp]) = u;
            }
        }
#pragma unroll
        for (int p = 0; p < 3; p++)
#pragma unroll
            for (int c = 0; c < 2; c++) {
                int idx = c * 256 + tid;
                int rw = idx >> 2, kp2 = (idx & 3) * 8;
                gl16(Ws[p] + (size_t)(bn + rw) * HID + k0 + kp2,
                     &Bs[p][c * 2048 + w * 512]);
            }
        __syncthreads();
#pragma unroll
        for (int p = 0; p < 3; p++) {
            s16x8 af[2], bf4[4];
#pragma unroll
            for (int i = 0; i < 2; i++)
                af[i] = *reinterpret_cast<const s16x8*>(
                    &As[p][(wm * 32 + i * 16 + lr) * 32 + lk]);
#pragma unroll
            for (int j = 0; j < 4; j++)
                bf4[j] = *reinterpret_cast<const s16x8*>(
                    &Bs[p][(wn * 64 + j * 16 + lr) * 32 + lk]);
#pragma unroll
            for (int i = 0; i < 2; i++)
#pragma unroll
                for (int j = 0; j < 4; j++)
                    acc[p][i][j] = MF(af[i], bf4[j], acc[p][i][j]);
        }
        __syncthreads();
    }

    unsigned short* dsts[3] = {Ro, Ko, Vo};
#pragma unroll
    for (int p = 0; p < 3; p++)
#pragma unroll
        for (int i = 0; i < 2; i++)
#pragma unroll
            for (int j = 0; j < 4; j++)
#pragma unroll
                for (int q = 0; q < 4; q++) {
                    const int grow = bm + wm * 32 + i * 16 + lq * 4 + q;
                    const int gcol = bn + wn * 64 + j * 16 + lr;
                    dsts[p][(size_t)grow * HID + gcol] = bfr(acc[p][i][j][q]);
                }
}

// ---------------------------------------------------------------------------
// lora4 (unchanged): fused v/w/a/g lora stage-1 -> H1[BTOT][352].
// ---------------------------------------------------------------------------
__global__ __launch_bounds__(256) void lora4_kernel(
        const float* __restrict__ x,
        const float* __restrict__ cv_, const float* __restrict__ cw_,
        const float* __restrict__ ca_, const float* __restrict__ cg_,
        const unsigned short* __restrict__ LW, unsigned short* __restrict__ H1) {
    __shared__ __align__(16) unsigned short As[4][64 * 32];
    __shared__ __align__(16) unsigned short Bs[L4N * 32];
    const int tid = threadIdx.x;
    const int w = tid >> 6, l = tid & 63;
    const int lr = l & 15, lq = l >> 4, lk = lq * 8;
    const int bm = blockIdx.x * 64;
    const float* cvs[4] = {cv_, cw_, ca_, cg_};

    f32x4v acc[22];
#pragma unroll
    for (int j = 0; j < 22; j++)
#pragma unroll
        for (int q = 0; q < 4; q++) acc[j][q] = 0.f;

    for (int k0 = 0; k0 < HID; k0 += 32) {
        {
            const int row = tid >> 2, kp = (tid & 3) * 8;
            const int gr = bm + row;
            const float* xp = x + (size_t)gr * HID + k0 + kp;
            float4 x0 = ld4(xp), x1 = ld4(xp + 4);
            float4 p0 = make_float4(0.f, 0.f, 0.f, 0.f), p1 = p0;
            if ((gr & (TSEQ - 1)) != 0) { p0 = ld4(xp - HID); p1 = ld4(xp - HID + 4); }
            float xb[8] = {x0.x, x0.y, x0.z, x0.w, x1.x, x1.y, x1.z, x1.w};
            float dx[8] = {p0.x - x0.x, p0.y - x0.y, p0.z - x0.z, p0.w - x0.w,
                           p1.x - x1.x, p1.y - x1.y, p1.z - x1.z, p1.w - x1.w};
#pragma unroll
            for (int p = 0; p < 4; p++) {
                float4 c0 = ld4(cvs[p] + k0 + kp), c1 = ld4(cvs[p] + k0 + kp + 4);
                float cc[8] = {c0.x, c0.y, c0.z, c0.w, c1.x, c1.y, c1.z, c1.w};
                uint4 u;
                u.x = pk2(fmaf(dx[0], cc[0], xb[0]), fmaf(dx[1], cc[1], xb[1]));
                u.y = pk2(fmaf(dx[2], cc[2], xb[2]), fmaf(dx[3], cc[3], xb[3]));
                u.z = pk2(fmaf(dx[4], cc[4], xb[4]), fmaf(dx[5], cc[5], xb[5]));
                u.w = pk2(fmaf(dx[6], cc[6], xb[6]), fmaf(dx[7], cc[7], xb[7]));
                *reinterpret_cast<uint4*>(&As[p][row * 32 + kp]) = u;
            }
        }
#pragma unroll
        for (int c = 0; c < 6; c++) {
            int idx = c * 256 + tid;
            if (idx < L4N * 4) {
                gl16(LW + (size_t)(idx >> 2) * HID + (idx & 3) * 8 + k0,
                     (char*)&Bs[0] + (c * 256 + w * 64) * 16);
            }
        }
        __syncthreads();
        s16x8 af[4];
#pragma unroll
        for (int p = 0; p < 4; p++)
            af[p] = *reinterpret_cast<const s16x8*>(&As[p][(w * 16 + lr) * 32 + lk]);
#pragma unroll
        for (int j = 0; j < 22; j++) {
            const int grp = (j < 4) ? 0 : (j < 8) ? 1 : (j < 12) ? 2 : 3;
            s16x8 bf = *reinterpret_cast<const s16x8*>(&Bs[(j * 16 + lr) * 32 + lk]);
            acc[j] = MF(af[grp], bf, acc[j]);
        }
        __syncthreads();
    }

#pragma unroll
    for (int j = 0; j < 22; j++)
#pragma unroll
        for (int q = 0; q < 4; q++) {
            const int grow = bm + w * 16 + lq * 4 + q;
            const int gcol = j * 16 + lr;
            float d = acc[j][q];
            if (j >= 4 && j < 8) d = tanhf(d);
            else if (j >= 12) d = sigf(d);
            H1[(size_t)grow * L4N + gcol] = bfr(d);
        }
}

// ---------------------------------------------------------------------------
// stage2 (unchanged): v/w/a lora stage-2 in one launch (blockIdx.z).
// ---------------------------------------------------------------------------
__global__ __launch_bounds__(256) void stage2_kernel(
        const unsigned short* __restrict__ H1,
        const unsigned short* __restrict__ vB16, const unsigned short* __restrict__ wB16,
        const unsigned short* __restrict__ aB16,
        const float* __restrict__ vb, const float* __restrict__ wb,
        const float* __restrict__ ab,
        unsigned short* __restrict__ Vout, unsigned short* __restrict__ Wout,
        unsigned short* __restrict__ Aout,
        const unsigned short* __restrict__ aux1, const float* __restrict__ aux2) {
    const int z = blockIdx.z;
    const unsigned short* Bw = (z == 0) ? vB16 : (z == 1) ? wB16 : aB16;
    const float* bias = (z == 0) ? vb : (z == 1) ? wb : ab;
    unsigned short* Cout = (z == 0) ? Vout : (z == 1) ? Wout : Aout;
    const int aoff = z * 64;
    __shared__ __align__(16) unsigned short As[128 * 32];
    __shared__ __align__(16) unsigned short Bs[128 * 32];
    const int tid = threadIdx.x;
    const int w = tid >> 6, l = tid & 63;
    const int bm = blockIdx.x * 128, bn = blockIdx.y * 128;
    const int wm = w >> 1, wn = w & 1;
    const int lr = l & 15, lk = (l >> 4) * 8;

    f32x4v acc[4][4];
#pragma unroll
    for (int i = 0; i < 4; i++)
#pragma unroll
        for (int j = 0; j < 4; j++)
#pragma unroll
            for (int q = 0; q < 4; q++) acc[i][j][q] = 0.f;

    for (int k0 = 0; k0 < 64; k0 += 32) {
#pragma unroll
        for (int c = 0; c < 2; c++) {
            int idx = c * 256 + tid;
            int row = idx >> 2, kp = (idx & 3) * 8;
            gl16(H1 + (size_t)(bm + row) * L4N + aoff + k0 + kp,
                 &As[c * 2048 + w * 512]);
        }
#pragma unroll
        for (int c = 0; c < 2; c++) {
            int idx = c * 256 + tid;
            int row = idx >> 2, kp = (idx & 3) * 8;
            gl16(Bw + (size_t)(bn + row) * 64 + k0 + kp, &Bs[c * 2048 + w * 512]);
        }
        __syncthreads();
        s16x8 afx[4], bfx[4];
#pragma unroll
        for (int i = 0; i < 4; i++)
            afx[i] = *reinterpret_cast<const s16x8*>(&As[(wm * 64 + i * 16 + lr) * 32 + lk]);
#pragma unroll
        for (int j = 0; j < 4; j++)
            bfx[j] = *reinterpret_cast<const s16x8*>(&Bs[(wn * 64 + j * 16 + lr) * 32 + lk]);
#pragma unroll
        for (int i = 0; i < 4; i++)
#pragma unroll
            for (int j = 0; j < 4; j++)
                acc[i][j] = MF(afx[i], bfx[j], acc[i][j]);
        __syncthreads();
    }

#pragma unroll
    for (int i = 0; i < 4; i++) {
        const int grow0 = bm + wm * 64 + i * 16 + (l >> 4) * 4;
#pragma unroll
        for (int j = 0; j < 4; j++) {
            const int gcol = bn + wn * 64 + j * 16 + lr;
            const float bsv = bias[gcol];
#pragma unroll
            for (int q = 0; q < 4; q++) {
                const int grow = grow0 + q;
                float d = acc[i][j][q];
                if (z == 0) {
                    float v0 = bff(aux1[(size_t)grow * HID + gcol]);
                    d = fmaf(aux2[(size_t)grow * HID + gcol] - v0, sigf(d + bsv), v0);
                } else if (z == 1) {
                    d = W_SCALE * sigf(d + bsv);
                } else {
                    d = sigf(d + bsv);
                }
                Cout[(size_t)grow * HID + gcol] = bfr(d);
            }
        }
    }
}

// ---------------------------------------------------------------------------
// mgemm (unchanged; the g stage-2).
// ---------------------------------------------------------------------------
template<int BM, int BN, int MODE, bool OUTBF>
__global__ __launch_bounds__(256) void mgemm(
        const unsigned short* __restrict__ Ab, const unsigned short* __restrict__ Bw,
        void* Cout, int N, int K, int lda,
        const float* __restrict__ bias,
        const unsigned short* aux1, const float* __restrict__ aux2) {
    constexpr int BK = 32;
    constexpr int WM_ = (BN == 128) ? 2 : 4;
    constexpr int WN_ = (BN == 128) ? 2 : 1;
    constexpr int WTM = BM / WM_, WTN = BN / WN_;
    constexpr int MF_ = WTM / 16, NF = WTN / 16;
    constexpr int ACALLS = (BM * BK) / 2048;
    constexpr int BCALLS = (BN * BK) / 2048;
    __shared__ __align__(16) unsigned short As[BM * BK];
    __shared__ __align__(16) unsigned short Bs[BN * BK];
    const int tid = threadIdx.x;
    const int w = tid >> 6, l = tid & 63;
    const int bm = blockIdx.x * BM, bn = blockIdx.y * BN;
    const int wm = w / WN_, wn = w % WN_;
    const int lr = l & 15, lk = (l >> 4) * 8;

    f32x4v acc[MF_][NF];
#pragma unroll
    for (int i = 0; i < MF_; i++)
#pragma unroll
        for (int j = 0; j < NF; j++)
#pragma unroll
            for (int q = 0; q < 4; q++) acc[i][j][q] = 0.f;

    for (int k0 = 0; k0 < K; k0 += BK) {
#pragma unroll
        for (int c = 0; c < ACALLS; c++) {
            int idx = c * 256 + tid;
            int row = idx >> 2, kp = (idx & 3) * 8;
            gl16(Ab + (size_t)(bm + row) * lda + k0 + kp, &As[c * 2048 + w * 512]);
        }
#pragma unroll
        for (int c = 0; c < BCALLS; c++) {
            int idx = c * 256 + tid;
            int row = idx >> 2, kp = (idx & 3) * 8;
            int gc = bn + row; if (gc > N - 1) gc = N - 1;
            gl16(Bw + (size_t)gc * K + k0 + kp, &Bs[c * 2048 + w * 512]);
        }
        __syncthreads();
        s16x8 afx[MF_], bfx[NF];
#pragma unroll
        for (int i = 0; i < MF_; i++)
            afx[i] = *reinterpret_cast<const s16x8*>(&As[(wm * WTM + i * 16 + lr) * BK + lk]);
#pragma unroll
        for (int j = 0; j < NF; j++)
            bfx[j] = *reinterpret_cast<const s16x8*>(&Bs[(wn * WTN + j * 16 + lr) * BK + lk]);
#pragma unroll
        for (int i = 0; i < MF_; i++)
#pragma unroll
            for (int j = 0; j < NF; j++)
                acc[i][j] = __builtin_amdgcn_mfma_f32_16x16x32_bf16(
                    afx[i], bfx[j], acc[i][j], 0, 0, 0);
        __syncthreads();
    }

#pragma unroll
    for (int i = 0; i < MF_; i++) {
        const int grow0 = bm + wm * WTM + i * 16 + (l >> 4) * 4;
#pragma unroll
        for (int j = 0; j < NF; j++) {
            const int gcol = bn + wn * WTN + j * 16 + lr;
            if (gcol >= N) continue;
#pragma unroll
            for (int q = 0; q < 4; q++) {
                const int grow = grow0 + q;
                float d = acc[i][j][q];
                if (OUTBF) ((unsigned short*)Cout)[(size_t)grow * N + gcol] = bfr(d);
                else       ((float*)Cout)[(size_t)grow * N + gcol] = d;
            }
        }
    }
}

// ---------------------------------------------------------------------------
// rowprep: the serial scaling row loop ONLY, zero LDS (high occupancy).
// Reads k/a/r/w; writes At->KK16, Bt->A16, Kt->K16, Rt->R16, SB, Ed.
// grid 8192 x 64 thr (1 wave per (bh, chunk)).
// ---------------------------------------------------------------------------
__global__ __launch_bounds__(64) void rowprep_kernel(
        unsigned short* __restrict__ K16, unsigned short* __restrict__ A16,
        unsigned short* __restrict__ R16, unsigned short* __restrict__ KK16,
        const unsigned short* __restrict__ W16,
        const float* __restrict__ kkc, const float* __restrict__ kac,
        const float* __restrict__ rkw,
        float* __restrict__ SB, float* __restrict__ Ed) {
    const int bid = blockIdx.x;
    const int bh = bid >> 6, ch = bid & 63;
    const int bb = bh >> 4, hh = bh & 15;
    const int l = threadIdx.x;
    const int chn = hh * 64 + l;
    const float kkcv = kkc[chn], kacv = kac[chn], rkv = rkw[chn];
    size_t off = ((size_t)(bb * TSEQ) + ch * CCH) * HID + chn;
    float cw = 0.f, er = 1.f;
    for (int i = 0; i < CCH; i++, off += HID) {
        const float k = bff(K16[off]);
        const float a = bff(A16[off]);
        const float r = bff(R16[off]);
        const float wv = bff(W16[off]);
        const float kr = k * kkcv;
        float ss = kr * kr;
        ss += __shfl_xor(ss, 1);  ss += __shfl_xor(ss, 2);
        ss += __shfl_xor(ss, 4);  ss += __shfl_xor(ss, 8);
        ss += __shfl_xor(ss, 16); ss += __shfl_xor(ss, 32);
        const float inv = 1.0f / fmaxf(sqrtf(ss), 1e-12f);
        const float kk = kr * inv;
        const float b  = kk * a;
        const float kn = k * fmaf(a - 1.0f, kacv, 1.0f);
        float s3 = r * kn * rkv;
        s3 += __shfl_xor(s3, 1);  s3 += __shfl_xor(s3, 2);
        s3 += __shfl_xor(s3, 4);  s3 += __shfl_xor(s3, 8);
        s3 += __shfl_xor(s3, 16); s3 += __shfl_xor(s3, 32);
        if (l == 0) SB[(size_t)bh * TSEQ + ch * CCH + i] = s3;
        const float cwp = cw; cw += wv;
        const float ea = __expf(cwp), ei = __expf(-cw);
        er = __expf(cw);
        KK16[off] = bfr(-kk * ea);
        A16[off]  = bfr(b * ei);
        K16[off]  = bfr(kn * ei);
        R16[off]  = bfr(r * er);
    }
    Ed[((size_t)bh * NCH + ch) * 64 + l] = er;
}

// ---------------------------------------------------------------------------
// compose: Mab/Mak (MFMA, operands read directly from global, L2-hot),
// fsub -> Minv hi/lo, AM = Mnv@At -> KK16 (over At), LM = Mnv@Mak -> global.
// grid 8192 x 64 thr (1 wave).  LDS ~19.5 KB -> 8 blocks/CU.
// ---------------------------------------------------------------------------
__global__ __launch_bounds__(64) void compose_kernel(
        const unsigned short* __restrict__ BtG, const unsigned short* __restrict__ KtG,
        unsigned short* __restrict__ KK16,
        unsigned short* __restrict__ MvH, unsigned short* __restrict__ MvL) {
    __shared__ __align__(16) unsigned short AtT[64][40];
    __shared__ __align__(16) float Mab[32][36];
    __shared__ __align__(16) unsigned short MakTH[32][40], MakTL[32][40];
    __shared__ __align__(16) unsigned short MnvH[32][40], MnvL[32][40];
    const int bid = blockIdx.x;
    const int bh = bid >> 6, ch = bid & 63;
    const int bb = bh >> 4, hh = bh & 15;
    const size_t cbase = ((size_t)(bb * TSEQ) + ch * CCH) * HID + hh * 64;
    const int l = threadIdx.x;
    const int lr = l & 15, lq = l >> 4;
    // transpose At (rows are coalesced 128B reads) into AtT
    for (int i = 0; i < 32; i++)
        AtT[l][i] = KK16[cbase + (size_t)i * HID + l];
    f32x4v z4; z4[0] = z4[1] = z4[2] = z4[3] = 0.f;
    // Mab/Mak via MFMA with direct-global frags
#pragma unroll
    for (int mi = 0; mi < 2; mi++) {
        s16x8 a0 = *reinterpret_cast<const s16x8*>(
            KK16 + cbase + (size_t)(mi * 16 + lr) * HID + lq * 8);
        s16x8 a1 = *reinterpret_cast<const s16x8*>(
            KK16 + cbase + (size_t)(mi * 16 + lr) * HID + 32 + lq * 8);
#pragma unroll
        for (int ni = 0; ni < 2; ni++) {
            s16x8 b0 = *reinterpret_cast<const s16x8*>(
                BtG + cbase + (size_t)(ni * 16 + lr) * HID + lq * 8);
            s16x8 b1 = *reinterpret_cast<const s16x8*>(
                BtG + cbase + (size_t)(ni * 16 + lr) * HID + 32 + lq * 8);
            s16x8 k0 = *reinterpret_cast<const s16x8*>(
                KtG + cbase + (size_t)(ni * 16 + lr) * HID + lq * 8);
            s16x8 k1 = *reinterpret_cast<const s16x8*>(
                KtG + cbase + (size_t)(ni * 16 + lr) * HID + 32 + lq * 8);
            f32x4v m  = MF(a1, b1, MF(a0, b0, z4));
            f32x4v mk = MF(a1, k1, MF(a0, k0, z4));
#pragma unroll
            for (int q = 0; q < 4; q++) {
                int r = mi * 16 + lq * 4 + q, cc2 = ni * 16 + lr;
                Mab[r][cc2] = (cc2 < r) ? m[q] : 0.f;
                float vv = (cc2 < r) ? mk[q] : 0.f;
                unsigned short h = bfr(vv);
                MakTH[cc2][r] = h;
                MakTL[cc2][r] = bfr(vv - bff(h));
            }
        }
    }
    __syncthreads();
    // forward substitution -> Minv columns (lane j) -> hi/lo LDS
    const int j = l & 31;
    float m[32];
#pragma unroll
    for (int i = 0; i < 32; i++) m[i] = (i == j) ? 1.f : 0.f;
#pragma unroll
    for (int i = 1; i < 32; i++) {
        float p0 = 0.f, p1 = 0.f, p2 = 0.f, p3 = 0.f;
#pragma unroll
        for (int k4_ = 0; k4_ < 32; k4_ += 4) {
            if (k4_ >= i) break;
            float4 L4 = *reinterpret_cast<const float4*>(&Mab[i][k4_]);
            p0 = fmaf(L4.x, m[k4_ + 0], p0);
            if (k4_ + 1 < i) p1 = fmaf(L4.y, m[k4_ + 1], p1);
            if (k4_ + 2 < i) p2 = fmaf(L4.z, m[k4_ + 2], p2);
            if (k4_ + 3 < i) p3 = fmaf(L4.w, m[k4_ + 3], p3);
        }
        m[i] += (p0 + p1) + (p2 + p3);
    }
    if (l < 32) {
#pragma unroll
        for (int i = 0; i < 32; i++) {
            unsigned short h = bfr(m[i]);
            MnvH[i][j] = h;
            MnvL[i][j] = bfr(m[i] - bff(h));
        }
    }
    __syncthreads();
    // AM (MFMA) -> KK16 ; LM (MFMA) -> hi/lo global
    {
        unsigned short* dH = MvH + (size_t)(bh * NCH + ch) * 1024;
        unsigned short* dL = MvL + (size_t)(bh * NCH + ch) * 1024;
#pragma unroll
        for (int mi = 0; mi < 2; mi++) {
            s16x8 ah = *reinterpret_cast<const s16x8*>(&MnvH[mi * 16 + lr][lq * 8]);
            s16x8 al = *reinterpret_cast<const s16x8*>(&MnvL[mi * 16 + lr][lq * 8]);
#pragma unroll
            for (int n = 0; n < 4; n++) {
                s16x8 bt = *reinterpret_cast<const s16x8*>(&AtT[n * 16 + lr][lq * 8]);
                f32x4v am = MF(al, bt, MF(ah, bt, z4));
#pragma unroll
                for (int q = 0; q < 4; q++)
                    KK16[cbase + (size_t)(mi * 16 + lq * 4 + q) * HID + n * 16 + lr]
                        = bfr(am[q]);
            }
#pragma unroll
            for (int n = 0; n < 2; n++) {
                s16x8 mh = *reinterpret_cast<const s16x8*>(&MakTH[n * 16 + lr][lq * 8]);
                s16x8 ml = *reinterpret_cast<const s16x8*>(&MakTL[n * 16 + lr][lq * 8]);
                f32x4v lm = MF(ah, ml, MF(al, mh, MF(ah, mh, z4)));
#pragma unroll
                for (int q = 0; q < 4; q++) {
                    const int r = mi * 16 + lq * 4 + q, cc = n * 16 + lr;
                    unsigned short h = bfr(lm[q]);
                    dH[r * 32 + cc] = h;
                    dL[r * 32 + cc] = bfr(lm[q] - bff(h));
                }
            }
        }
    }
}

// ---------------------------------------------------------------------------
// Chunked recurrence v2 (unchanged R17/18): 2 compute phases / 3 barriers.
// ---------------------------------------------------------------------------
__global__ __launch_bounds__(256) void recchunk_kernel(
        const unsigned short* __restrict__ AMG, const unsigned short* __restrict__ BtG,
        const unsigned short* __restrict__ KtG, const unsigned short* __restrict__ RtG,
        const unsigned short* __restrict__ V16, const float* __restrict__ Ed,
        const unsigned short* __restrict__ LMH, const unsigned short* __restrict__ LML,
        unsigned short* __restrict__ Ob16) {
    __shared__ __align__(16) unsigned short stT[2][4][CCH][64];
    __shared__ __align__(16) unsigned short stMh[2][32][32], stMl[2][32][32];
    __shared__ __align__(16) unsigned short stV[2][CCH][16];
    __shared__ __align__(16) float stEd[2][64];
    __shared__ __align__(16) unsigned short Shi[16][74], Slo[16][74];
    __shared__ __align__(16) unsigned short BtT[64][42], KtT[64][42];
    __shared__ __align__(16) unsigned short VT[16][42];
    __shared__ __align__(16) unsigned short MrkH[32][42], MrkL[32][42];
    __shared__ __align__(16) unsigned short MrbH[32][42], MrbL[32][42];
    __shared__ __align__(16) unsigned short SATh[16][42], SATl[16][42];

    const int bid = blockIdx.x;
    const int vq = bid >> 7, bh = bid & 127;
    const int tid = threadIdx.x;
    const int w = tid >> 6, l = tid & 63;
    const int lr = l & 15, lq = l >> 4;
    const int bb = bh >> 4, hh = bh & 15;
    const size_t rowoff = ((size_t)bb * TSEQ) * HID + hh * 64;
    const int mi = w >> 1, ni = w & 1;

    const int r8 = l >> 3, ck = l & 7;
    const int swz8 = (ck ^ r8) * 8;

    auto STAGE = [&](int buf, int cn) {
        if (cn >= NCH) return;
        const size_t cb = rowoff + (size_t)(cn * CCH) * HID;
        const unsigned short* srcs[4] = {AMG, BtG, KtG, RtG};
        const unsigned short* T = srcs[w];
#pragma unroll
        for (int c = 0; c < 4; c++)
            gl16(T + cb + (size_t)(c * 8 + r8) * HID + swz8, &stT[buf][w][c * 8][0]);
        if (w == 0) {
            gl16(V16 + cb + (size_t)(l >> 1) * HID + vq * 16 + (l & 1) * 8,
                 &stV[buf][0][0]);
            gl4(Ed + ((size_t)bh * NCH + cn) * 64 + l, &stEd[buf][0]);
        } else if (w == 1) {
#pragma unroll
            for (int c = 0; c < 2; c++)
                gl16(LMH + (size_t)(bh * NCH + cn) * 1024 + c * 512 + l * 8,
                     (char*)&stMh[buf][0][0] + c * 1024);
        } else if (w == 2) {
#pragma unroll
            for (int c = 0; c < 2; c++)
                gl16(LML + (size_t)(bh * NCH + cn) * 1024 + c * 512 + l * 8,
                     (char*)&stMl[buf][0][0] + c * 1024);
        }
    };

    for (int idx = tid; idx < 16 * 74; idx += 256) {
        ((unsigned short*)Shi)[idx] = 0;
        ((unsigned short*)Slo)[idx] = 0;
    }
    STAGE(0, 0);
    asm volatile("s_waitcnt vmcnt(0)" ::: "memory");
    __syncthreads();

    auto fragT = [&](int bf, int tn, int rbase, int kb) -> s16x8 {
        int row = rbase + lr;
        int chv = ((kb >> 3) + lq) ^ (row & 7);
        return *reinterpret_cast<const s16x8*>(
            (const char*)&stT[bf][tn][0][0] + row * 128 + chv * 16);
    };
    auto fragS = [&](const unsigned short (*Sx)[74], int kb) -> s16x8 {
        return *reinterpret_cast<const s16x8*>(&Sx[lr][kb + lq * 8]);
    };
    auto frag42 = [&](const unsigned short (*T)[42], int rbase) -> s16x8 {
        return *reinterpret_cast<const s16x8*>(&T[rbase + lr][lq * 8]);
    };

    f32x4v Sacc;
#pragma unroll
    for (int q = 0; q < 4; q++) Sacc[q] = 0.f;
    f32x4v z4; z4[0] = z4[1] = z4[2] = z4[3] = 0.f;

    int buf = 0;
    for (int c = 0; c < NCH; c++) {
        STAGE(buf ^ 1, c + 1);
        {
            const int tt = tid & 31, g8 = tid >> 5;
            const int ch = g8 ^ (tt & 7);
            uint4 bu = *reinterpret_cast<const uint4*>(&stT[buf][1][tt][ch * 8]);
            uint4 ku = *reinterpret_cast<const uint4*>(&stT[buf][2][tt][ch * 8]);
            unsigned int bw[4] = {bu.x, bu.y, bu.z, bu.w};
            unsigned int kw[4] = {ku.x, ku.y, ku.z, ku.w};
#pragma unroll
            for (int e = 0; e < 4; e++) {
                BtT[g8 * 8 + 2 * e][tt]     = (unsigned short)(bw[e] & 0xffffu);
                BtT[g8 * 8 + 2 * e + 1][tt] = (unsigned short)(bw[e] >> 16);
                KtT[g8 * 8 + 2 * e][tt]     = (unsigned short)(kw[e] & 0xffffu);
                KtT[g8 * 8 + 2 * e + 1][tt] = (unsigned short)(kw[e] >> 16);
            }
            if (g8 < 4) {
                ushort4 vu = *reinterpret_cast<const ushort4*>(&stV[buf][tt][g8 * 4]);
                VT[g8 * 4 + 0][tt] = vu.x; VT[g8 * 4 + 1][tt] = vu.y;
                VT[g8 * 4 + 2][tt] = vu.z; VT[g8 * 4 + 3][tt] = vu.w;
            }
        }
        __syncthreads();
        f32x4v oac = z4;
        if (ni == 0) {
            s16x8 rt0 = fragT(buf, 3, mi * 16, 0), rt1 = fragT(buf, 3, mi * 16, 32);
            s16x8 sh0 = fragS(Shi, 0), sh1 = fragS(Shi, 32);
            s16x8 sl0 = fragS(Slo, 0), sl1 = fragS(Slo, 32);
            oac = MF(rt1, sl1, MF(rt0, sl0, MF(rt1, sh1, MF(rt0, sh0, z4))));
#pragma unroll
            for (int n = 0; n < 2; n++) {
                s16x8 kt0 = fragT(buf, 2, n * 16, 0), kt1 = fragT(buf, 2, n * 16, 32);
                s16x8 bt0 = fragT(buf, 1, n * 16, 0), bt1 = fragT(buf, 1, n * 16, 32);
                f32x4v mrk = MF(rt1, kt1, MF(rt0, kt0, z4));
                f32x4v mrb = MF(rt1, bt1, MF(rt0, bt0, z4));
#pragma unroll
                for (int q = 0; q < 4; q++) {
                    const int r = mi * 16 + lq * 4 + q, cc = n * 16 + lr;
                    float vv = (cc <= r) ? mrk[q] : 0.f;
                    unsigned short h = bfr(vv);
                    MrkH[r][cc] = h; MrkL[r][cc] = bfr(vv - bff(h));
                    vv = (cc <= r) ? mrb[q] : 0.f; h = bfr(vv);
                    MrbH[r][cc] = h; MrbL[r][cc] = bfr(vv - bff(h));
                }
            }
        } else {
            s16x8 am0 = fragT(buf, 0, mi * 16, 0), am1 = fragT(buf, 0, mi * 16, 32);
            s16x8 sh0 = fragS(Shi, 0), sh1 = fragS(Shi, 32);
            s16x8 sl0 = fragS(Slo, 0), sl1 = fragS(Slo, 32);
            s16x8 vt0 = frag42(VT, 0);
            s16x8 lmh = *reinterpret_cast<const s16x8*>(&stMh[buf][mi * 16 + lr][lq * 8]);
            s16x8 lml = *reinterpret_cast<const s16x8*>(&stMl[buf][mi * 16 + lr][lq * 8]);
            f32x4v sat = MF(sl1, am1, MF(sl0, am0, MF(sh1, am1, MF(sh0, am0, z4))));
            sat = MF(vt0, lml, MF(vt0, lmh, sat));
#pragma unroll
            for (int q = 0; q < 4; q++) {
                const int r = lq * 4 + q, cc = mi * 16 + lr;
                unsigned short h = bfr(sat[q]);
                SATh[r][cc] = h;
                SATl[r][cc] = bfr(sat[q] - bff(h));
            }
        }
        __syncthreads();
        if (ni == 0) {
            s16x8 vt0 = frag42(VT, 0);
            oac = MF(frag42(MrkL, mi * 16), vt0,
                     MF(frag42(MrkH, mi * 16), vt0, oac));
            s16x8 sath = frag42(SATh, 0), satl = frag42(SATl, 0);
            s16x8 rbh = frag42(MrbH, mi * 16), rbl = frag42(MrbL, mi * 16);
            oac = MF(rbl, sath, MF(rbh, satl, MF(rbh, sath, oac)));
#pragma unroll
            for (int q = 0; q < 4; q++) {
                const int t = c * CCH + mi * 16 + lq * 4 + q;
                Ob16[rowoff + (size_t)t * HID + vq * 16 + lr] = bfr(oac[q]);
            }
        }
        {
            s16x8 sath = frag42(SATh, 0), satl = frag42(SATl, 0);
            s16x8 btf = frag42(BtT, w * 16);
            s16x8 ktf = frag42(KtT, w * 16);
            s16x8 vta = frag42(VT, 0);
            const float ed = stEd[buf][w * 16 + lr];
            Sacc = MF(sath, btf, Sacc);
            Sacc = MF(satl, btf, Sacc);
            Sacc = MF(vta, ktf, Sacc);
#pragma unroll
            for (int q = 0; q < 4; q++) {
                Sacc[q] *= ed;
                unsigned short h = bfr(Sacc[q]);
                Shi[lq * 4 + q][w * 16 + lr] = h;
                Slo[lq * 4 + q][w * 16 + lr] = bfr(Sacc[q] - bff(h));
            }
        }
        asm volatile("s_waitcnt vmcnt(0)" ::: "memory");
        __syncthreads();
        buf ^= 1;
    }
}

// ---------------------------------------------------------------------------
// stats (unchanged): per (row, head) mu, rsqrt -> MS (= dead Ed region).
// ---------------------------------------------------------------------------
__global__ __launch_bounds__(256) void stats_kernel(
        const unsigned short* __restrict__ O16, float* __restrict__ MS) {
    const int row = blockIdx.x;
    const int tid = threadIdx.x;
    const int c = tid * 4;
    ushort4 ou = *reinterpret_cast<const ushort4*>(O16 + (size_t)row * HID + c);
    float o[4] = {bff(ou.x), bff(ou.y), bff(ou.z), bff(ou.w)};
    float s1 = o[0] + o[1] + o[2] + o[3];
    float s2 = o[0]*o[0] + o[1]*o[1] + o[2]*o[2] + o[3]*o[3];
#pragma unroll
    for (int m = 1; m < 16; m <<= 1) {
        s1 += __shfl_xor(s1, m); s2 += __shfl_xor(s2, m);
    }
    if ((tid & 15) == 0) {
        const int hh = tid >> 4;
        const float mu = s1 * (1.0f / 64.0f);
        const float var = s2 * (1.0f / 64.0f) - mu * mu;
        float2 v; v.x = mu; v.y = rsqrtf(var + GN_EPS);
        *reinterpret_cast<float2*>(MS + (size_t)row * 32 + hh * 2) = v;
    }
}

// ---------------------------------------------------------------------------
// wogemm (unchanged): out = y @ W_o^T with fused y-compute in A-staging.
// ---------------------------------------------------------------------------
__global__ __launch_bounds__(256) void wogemm_kernel(
        const unsigned short* __restrict__ O16, const unsigned short* __restrict__ V16,
        const unsigned short* __restrict__ G16, const float* __restrict__ SB,
        const float* __restrict__ MS, const float* __restrict__ gnw,
        const float* __restrict__ gnb, const unsigned short* __restrict__ Wo,
        float* __restrict__ out) {
    __shared__ __align__(16) unsigned short As[128 * 32];
    __shared__ __align__(16) unsigned short Bs[128 * 32];
    const int tid = threadIdx.x;
    const int w = tid >> 6, l = tid & 63;
    const int bm = blockIdx.x * 128, bn = blockIdx.y * 128;
    const int wm = w >> 1, wn = w & 1;
    const int lr = l & 15, lk = (l >> 4) * 8;

    f32x4v acc[4][4];
#pragma unroll
    for (int i = 0; i < 4; i++)
#pragma unroll
        for (int j = 0; j < 4; j++)
#pragma unroll
            for (int q = 0; q < 4; q++) acc[i][j][q] = 0.f;

    for (int k0 = 0; k0 < HID; k0 += 32) {
#pragma unroll
        for (int c = 0; c < 2; c++) {
            int idx = c * 256 + tid;
            int row = idx >> 2, kp = (idx & 3) * 8;
            const int gr = bm + row;
            const size_t rb = (size_t)gr * HID + k0 + kp;
            uint4 ou = *reinterpret_cast<const uint4*>(O16 + rb);
            uint4 vu = *reinterpret_cast<const uint4*>(V16 + rb);
            uint4 gu = *reinterpret_cast<const uint4*>(G16 + rb);
            float o8[8], v8[8], g8[8];
            up8(ou, o8); up8(vu, v8); up8(gu, g8);
            const int hh = (k0 + kp) >> 6;
            float2 ms = *reinterpret_cast<const float2*>(MS + (size_t)gr * 32 + hh * 2);
            const float s3 = SB[((size_t)(gr >> 11) * 16 + hh) * TSEQ + (gr & (TSEQ - 1))];
            float4 w0 = ld4(gnw + k0 + kp), w1 = ld4(gnw + k0 + kp + 4);
            float4 b0 = ld4(gnb + k0 + kp), b1 = ld4(gnb + k0 + kp + 4);
            float wn8[8] = {w0.x, w0.y, w0.z, w0.w, w1.x, w1.y, w1.z, w1.w};
            float bn8[8] = {b0.x, b0.y, b0.z, b0.w, b1.x, b1.y, b1.z, b1.w};
            float y[8];
#pragma unroll
            for (int e = 0; e < 8; e++)
                y[e] = (fmaf((o8[e] - ms.x) * ms.y, wn8[e], bn8[e]) + s3 * v8[e]) * g8[e];
            uint4 u;
            u.x = pk2(y[0], y[1]); u.y = pk2(y[2], y[3]);
            u.z = pk2(y[4], y[5]); u.w = pk2(y[6], y[7]);
            *reinterpret_cast<uint4*>(&As[idx * 8]) = u;
        }
#pragma unroll
        for (int c = 0; c < 2; c++) {
            int idx = c * 256 + tid;
            int row = idx >> 2, kp = (idx & 3) * 8;
            gl16(Wo + (size_t)(bn + row) * HID + k0 + kp, &Bs[c * 2048 + w * 512]);
        }
        __syncthreads();
        s16x8 afx[4], bfx[4];
#pragma unroll
        for (int i = 0; i < 4; i++)
            afx[i] = *reinterpret_cast<const s16x8*>(&As[(wm * 64 + i * 16 + lr) * 32 + lk]);
#pragma unroll
        for (int j = 0; j < 4; j++)
            bfx[j] = *reinterpret_cast<const s16x8*>(&Bs[(wn * 64 + j * 16 + lr) * 32 + lk]);
#pragma unroll
        for (int i = 0; i < 4; i++)
#pragma unroll
            for (int j = 0; j < 4; j++)
                acc[i][j] = MF(afx[i], bfx[j], acc[i][j]);
        __syncthreads();
    }

#pragma unroll
    for (int i = 0; i < 4; i++) {
        const int grow0 = bm + wm * 64 + i * 16 + (l >> 4) * 4;
#pragma unroll
        for (int j = 0; j < 4; j++) {
            const int gcol = bn + wn * 64 + j * 16 + lr;
#pragma unroll
            for (int q = 0; q < 4; q++)
                out[(size_t)(grow0 + q) * HID + gcol] = acc[i][j][q];
        }
    }
}

// ---------------------------------------------------------------------------
extern "C" void kernel_launch(void* const* d_in, const int* in_sizes, int n_in,
                              void* d_out, int out_size, void* d_ws, size_t ws_size,
                              hipStream_t stream) {
    const float* x   = (const float*)d_in[0];
    const float* vf  = (const float*)d_in[1];
    const float* x_r = (const float*)d_in[2];
    const float* x_w = (const float*)d_in[3];
    const float* x_k = (const float*)d_in[4];
    const float* x_v = (const float*)d_in[5];
    const float* x_a = (const float*)d_in[6];
    const float* x_g = (const float*)d_in[7];
    const float* k_k = (const float*)d_in[8];
    const float* k_a = (const float*)d_in[9];
    const float* r_k = (const float*)d_in[10];
    const float* W_r = (const float*)d_in[11];
    const float* W_k = (const float*)d_in[12];
    const float* W_v = (const float*)d_in[13];
    const float* W_o = (const float*)d_in[14];
    const float* wA  = (const float*)d_in[15];
    const float* wB  = (const float*)d_in[16];
    const float* wb  = (const float*)d_in[17];
    const float* aA  = (const float*)d_in[18];
    const float* aB  = (const float*)d_in[19];
    const float* ab  = (const float*)d_in[20];
    const float* vA  = (const float*)d_in[21];
    const float* vB  = (const float*)d_in[22];
    const float* vb  = (const float*)d_in[23];
    const float* gA  = (const float*)d_in[24];
    const float* gB  = (const float*)d_in[25];
    const float* gnw = (const float*)d_in[26];
    const float* gnb = (const float*)d_in[27];
    float* out = (float*)d_out;

    float* ws = (float*)d_ws;
    const size_t SZ = (size_t)BTOT * HID;
    const size_t HH = (size_t)HID * HID;
    float*          REG  = ws;   // 64MB: [W16|O16 first 32MB][LM|G16 last 32MB]
    unsigned short* P    = (unsigned short*)(ws + SZ);
    unsigned short* R16  = P;
    unsigned short* K16  = P + 1 * SZ;
    unsigned short* V16  = P + 2 * SZ;
    unsigned short* A16  = P + 3 * SZ;
    unsigned short* KK16 = P + 4 * SZ;   // At -> AM
    unsigned short* H1   = P + 5 * SZ;               // [BTOT][352]
    unsigned short* WR   = H1 + (size_t)BTOT * L4N;
    unsigned short* Wr16 = WR;
    unsigned short* Wk16 = WR + 1 * HH;
    unsigned short* Wv16 = WR + 2 * HH;
    unsigned short* Wo16 = WR + 3 * HH;
    unsigned short* LW   = WR + 4 * HH;              // [352][1024]
    unsigned short* vB16 = LW + (size_t)L4N * HID;
    unsigned short* wB16 = vB16 + 65536;
    unsigned short* aB16 = wB16 + 65536;
    unsigned short* gB16 = aB16 + 65536;
    float*          SB   = (float*)(gB16 + 163840);  // [128][2048]
    float*          Ed   = SB + (size_t)128 * TSEQ;  // [128][64][64]
    float*          MS   = Ed;   // ALIAS: Ed dead after recchunk
    unsigned short* W16   = (unsigned short*)REG;          // decay (pre-rowprep)
    unsigned short* O16   = (unsigned short*)REG;          // o (post-compose)
    unsigned short* LMHp  = (unsigned short*)(REG + 8 * 1024 * 1024);
    unsigned short* LMLp  = LMHp + (size_t)128 * NCH * 1024;
    unsigned short* G16   = (unsigned short*)(REG + 8 * 1024 * 1024);  // post-rec

    const dim3 blk(256);
    const dim3 gBig(128, 8);
    const dim3 gP3(BTOT / 64, 8);
    const unsigned short* nu = nullptr;
    const float* np = nullptr;

    // --- single cast launch (prefix-offset table) ---
    CastArgs ca;
    const float* srcs[12] = {W_r, W_k, W_v, W_o, vA, wA, aA, gA, vB, wB, aB, gB};
    unsigned short* dsts[12] = {Wr16, Wk16, Wv16, Wo16,
                                LW, LW + 65536, LW + 131072, LW + 196608,
                                vB16, wB16, aB16, gB16};
    int cnts[12] = {(int)HH, (int)HH, (int)HH, (int)HH,
                    65536, 65536, 65536, 163840, 65536, 65536, 65536, 163840};
    int acc4 = 0;
    for (int s = 0; s < 12; s++) {
        ca.src[s] = srcs[s]; ca.dst[s] = dsts[s];
        ca.start4[s] = acc4;
        acc4 += cnts[s] / 4;
    }
    ca.start4[12] = acc4;
    cast_all_kernel<<<dim3((acc4 + 255) / 256), blk, 0, stream>>>(ca);

    // fused r, k, v0 projections
    proj3_kernel<<<gP3, blk, 0, stream>>>(
        x, x_r, x_k, x_v, Wr16, Wk16, Wv16, R16, K16, V16);
    // fused lora stage-1 (v,w,a,g) -> H1
    lora4_kernel<<<dim3(BTOT / 64), blk, 0, stream>>>(
        x, x_v, x_w, x_a, x_g, LW, H1);
    // v/w/a stage-2 in one launch
    stage2_kernel<<<dim3(128, 8, 3), blk, 0, stream>>>(
        H1, vB16, wB16, aB16, vb, wb, ab, V16, W16, A16, V16, vf);
    // rowprep (zero-LDS, high occupancy): scaling + prefix + s3/Ed
    rowprep_kernel<<<dim3(128 * NCH), dim3(64), 0, stream>>>(
        K16, A16, R16, KK16, W16, k_k, k_a, r_k, SB, Ed);
    // compose: Mab/Mak/Minv + folded AM/LM (MFMA)
    compose_kernel<<<dim3(128 * NCH), dim3(64), 0, stream>>>(
        A16, K16, KK16, LMHp, LMLp);
    // chunked recurrence -> o bf16 (O16 over dead W16 region)
    recchunk_kernel<<<dim3(512), blk, 0, stream>>>(
        KK16, A16, K16, R16, V16, Ed, LMHp, LMLp, O16);
    // g = h_g @ gB^T (bf16, over dead LM region)
    mgemm<128,128,0,true><<<gBig, blk, 0, stream>>>(
        H1 + 192, gB16, G16, HID, 160, L4N, np, nu, np);
    // GroupNorm stats (MS over dead Ed region)
    stats_kernel<<<dim3(BTOT), blk, 0, stream>>>(O16, MS);
    // out = y @ W_o^T with fused y-compute
    wogemm_kernel<<<gBig, blk, 0, stream>>>(
        O16, V16, G16, SB, MS, gnw, gnb, Wo16, out);
    (void)in_sizes; (void)n_in; (void)out_size; (void)ws_size;
}